// Round 20
// baseline (177.773 us; speedup 1.0000x reference)
//
#include <hip/hip_runtime.h>

typedef unsigned short u16;
typedef unsigned int u32;
typedef __attribute__((ext_vector_type(8))) short bh8;   // 8 x bf16 raw bits
typedef __attribute__((ext_vector_type(4))) float fx4;
typedef __attribute__((ext_vector_type(4))) short s4;
typedef __attribute__((ext_vector_type(2))) unsigned int u32x2;

#define QS 0.2550437194342803f   /* (1/sqrt(32)) * log2(e) */

__device__ __forceinline__ u16 f2bf(float f) {
    unsigned u = __float_as_uint(f);
    u += 0x7fffu + ((u >> 16) & 1u);   // round-to-nearest-even
    return (u16)(u >> 16);
}

__device__ __forceinline__ float bf2f(u16 b) {
    return __uint_as_float((u32)b << 16);
}

__device__ __forceinline__ u32 cvtpk(float lo, float hi) {
    u32 r;
    asm("v_cvt_pk_bf16_f32 %0, %1, %2" : "=v"(r) : "v"(lo), "v"(hi));
    return r;
}

// ------------------------------------------------------------------
// prep: x -> bf16; counts zeroed; weights transposed via tiled 64x64
// LDS transpose; fused QKV weight/bias with Q pre-scaled by QS.
// grid = 128 (x) + 16 (counts) + 1 (bias) + 304 tiles = 449 blocks
// ------------------------------------------------------------------
__global__ __launch_bounds__(256) void prep_kernel(
    const float* x, const float* ew1, const float* ew2, const float* gw,
    const float* wq, const float* wk, const float* wv, const float* wo,
    const float* w1, const float* w2,
    const float* bq, const float* bk, const float* bv,
    u16* xb, u16* ew1t, u16* ew2t, u16* gwt,
    u16* wqkvt, float* bqkv, u16* wot, u16* w1t, u16* w2t,
    int* counts)
{
    __shared__ u16 tile[64 * 65];
    int bid = blockIdx.x;
    const int t = threadIdx.x;

    if (bid < 128) {   // x convert: 1M floats
        const float4* x4 = (const float4*)x;
        s4* o4 = (s4*)xb;
        #pragma unroll
        for (int i = 0; i < 8; i++) {
            int fi = bid * 2048 + i * 256 + t;
            float4 v = x4[fi];
            s4 o = { (short)f2bf(v.x), (short)f2bf(v.y), (short)f2bf(v.z), (short)f2bf(v.w) };
            o4[fi] = o;
        }
        return;
    }
    bid -= 128;
    if (bid < 16) {    // zero counts[4096]
        counts[bid * 256 + t] = 0;
        return;
    }
    bid -= 16;
    if (bid < 1) {     // bqkv [2][384]
        for (int idx = t; idx < 768; idx += 256) {
            int l = idx / 384, n = idx % 384;
            float v;
            if (n < 128)      v = bq[l * 128 + n] * QS;
            else if (n < 256) v = bk[l * 128 + n - 128];
            else              v = bv[l * 128 + n - 256];
            bqkv[idx] = v;
        }
        return;
    }
    bid -= 1;

    const float* src; u16* dst; int R, C, tr, tc; float sc = 1.f;
    if (bid < 8)            { src = ew1; dst = ew1t; R = 256; C = 128; tr = bid >> 1; tc = bid & 1; }
    else if ((bid -= 8) < 4)  { src = ew2; dst = ew2t; R = 128; C = 128; tr = bid >> 1; tc = bid & 1; }
    else if ((bid -= 4) < 4)  { src = gw;  dst = gwt;  R = 128; C = 128; tr = bid >> 1; tc = bid & 1; }
    else if ((bid -= 4) < 24) {
        int l = bid / 12, r2 = bid % 12, which = r2 >> 2, i = r2 & 3;
        R = 128; C = 128; tr = i >> 1; tc = i & 1;
        if (which == 0)      { src = wq + l * 16384; dst = wqkvt + l * 49152;         sc = QS; }
        else if (which == 1) { src = wk + l * 16384; dst = wqkvt + l * 49152 + 16384; }
        else                 { src = wv + l * 16384; dst = wqkvt + l * 49152 + 32768; }
    }
    else if ((bid -= 24) < 8)   { int l = bid >> 2, i = bid & 3;  src = wo + l * 16384; dst = wot + l * 16384; R = 128; C = 128; tr = i >> 1; tc = i & 1; }
    else if ((bid -= 8) < 128)  { int l = bid >> 6, i = bid & 63; src = w1 + (size_t)l * 262144; dst = w1t + (size_t)l * 262144; R = 128;  C = 2048; tr = i & 1;  tc = i >> 1; }
    else { bid -= 128;            int l = bid >> 6, i = bid & 63; src = w2 + (size_t)l * 262144; dst = w2t + (size_t)l * 262144; R = 2048; C = 128;  tr = i >> 1; tc = i & 1; }

    const int r = t >> 2, cs = (t & 3) * 16;
    const float* sp = src + (size_t)(tr * 64 + r) * C + tc * 64 + cs;
    #pragma unroll
    for (int j = 0; j < 16; j++) tile[r * 65 + cs + j] = f2bf(sp[j] * sc);
    __syncthreads();
    u16* dp = dst + (size_t)(tc * 64 + r) * R + tr * 64 + cs;
    #pragma unroll
    for (int j = 0; j < 16; j++) dp[j] = tile[(cs + j) * 65 + r];
}

// ------------------------------------------------------------------
// staged bf16 MFMA GEMM (64x64 tile) — used for QKV
// ------------------------------------------------------------------
__global__ __launch_bounds__(256) void gemm_bf16(
    const u16* __restrict__ A, const u16* __restrict__ Bt,
    const float* __restrict__ bias,
    float* __restrict__ Cf, u16* __restrict__ Cb, float* __restrict__ Cpart,
    u16* __restrict__ Cvt,
    int M, int N, int K, int relu, int kchunk, int ldc)
{
    __shared__ __align__(16) u16 As[2][64][40];
    __shared__ __align__(16) u16 Bs[2][64][40];
    const int m0 = blockIdx.x * 64, n0 = blockIdx.y * 64, z = blockIdx.z;
    const int tid = threadIdx.x;
    const int lane = tid & 63, w = tid >> 6;
    const int wm = (w >> 1) * 32, wn = (w & 1) * 32;
    const int l15 = lane & 15, l4 = lane >> 4;
    const int srow = tid >> 2, skq = (tid & 3) * 8;
    const int k0 = z * kchunk;

    const u16* Ap = A + (size_t)(m0 + srow) * K + k0 + skq;
    const u16* Bp = Bt + (size_t)(n0 + srow) * K + k0 + skq;

    fx4 acc00 = {0,0,0,0}, acc01 = {0,0,0,0}, acc10 = {0,0,0,0}, acc11 = {0,0,0,0};

    *(int4*)&As[0][srow][skq] = *(const int4*)Ap;
    *(int4*)&Bs[0][srow][skq] = *(const int4*)Bp;

    const int niter = kchunk >> 5;
    for (int it = 0; it < niter; it++) {
        const int cur = it & 1;
        int4 ar, br;
        __syncthreads();
        if (it + 1 < niter) {
            ar = *(const int4*)(Ap + (it + 1) * 32);
            br = *(const int4*)(Bp + (it + 1) * 32);
        }
        bh8 a0 = *(const bh8*)&As[cur][wm + l15][l4 * 8];
        bh8 a1 = *(const bh8*)&As[cur][wm + 16 + l15][l4 * 8];
        bh8 b0 = *(const bh8*)&Bs[cur][wn + l15][l4 * 8];
        bh8 b1 = *(const bh8*)&Bs[cur][wn + 16 + l15][l4 * 8];
        acc00 = __builtin_amdgcn_mfma_f32_16x16x32_bf16(a0, b0, acc00, 0, 0, 0);
        acc01 = __builtin_amdgcn_mfma_f32_16x16x32_bf16(a0, b1, acc01, 0, 0, 0);
        acc10 = __builtin_amdgcn_mfma_f32_16x16x32_bf16(a1, b0, acc10, 0, 0, 0);
        acc11 = __builtin_amdgcn_mfma_f32_16x16x32_bf16(a1, b1, acc11, 0, 0, 0);
        if (it + 1 < niter) {
            *(int4*)&As[cur ^ 1][srow][skq] = ar;
            *(int4*)&Bs[cur ^ 1][srow][skq] = br;
        }
    }

    fx4* accs[2][2] = {{&acc00, &acc01}, {&acc10, &acc11}};
    #pragma unroll
    for (int i = 0; i < 2; i++)
        #pragma unroll
        for (int j = 0; j < 2; j++) {
            int colg = n0 + wn + j * 16 + l15;
            int rowb = m0 + wm + i * 16 + l4 * 4;
            if (Cpart) {
                float* cp = Cpart + (size_t)z * M * N;
                #pragma unroll
                for (int r = 0; r < 4; r++)
                    cp[(size_t)(rowb + r) * N + colg] = (*accs[i][j])[r];
                continue;
            }
            float bvv = bias ? bias[colg] : 0.f;
            float vals[4];
            #pragma unroll
            for (int r = 0; r < 4; r++) {
                float v = (*accs[i][j])[r] + bvv;
                vals[r] = relu ? fmaxf(v, 0.f) : v;
            }
            if (Cvt && colg >= 256) {
                s4 pk = { (short)f2bf(vals[0]), (short)f2bf(vals[1]),
                          (short)f2bf(vals[2]), (short)f2bf(vals[3]) };
                *(s4*)&Cvt[(size_t)(colg - 256) * 4096 + rowb] = pk;
            } else {
                #pragma unroll
                for (int r = 0; r < 4; r++) {
                    if (Cf) Cf[(size_t)(rowb + r) * ldc + colg] = vals[r];
                    if (Cb) Cb[(size_t)(rowb + r) * ldc + colg] = f2bf(vals[r]);
                }
            }
        }
}

// ------------------------------------------------------------------
// FULL encoder + GAT front-end fusion + edge counting:
// h1 = relu(x @ ew1t^T + eb1); hb = h1 @ ew2t^T + eb2 (LDS only);
// hh = hb @ gwt^T -> global BF16; a_src/a_dst dots; then grid-stride
// count_edges atomics (counts pre-zeroed in prep).
// grid 128 x 256 thr; BM=32, BN=128.
// ------------------------------------------------------------------
__global__ __launch_bounds__(256) void encoder_gat(
    const u16* __restrict__ xb, const u16* __restrict__ ew1t,
    const float* __restrict__ eb1,
    const u16* __restrict__ ew2t, const float* __restrict__ eb2,
    const u16* __restrict__ gwt,
    const float* __restrict__ gasrc, const float* __restrict__ gadst,
    u16* __restrict__ hhb, float* __restrict__ ansrc,
    float* __restrict__ andst, int* __restrict__ counts,
    const int* __restrict__ edst, int E)
{
    __shared__ __align__(16) u16 As[32][264];
    __shared__ __align__(16) u16 Bs[2][128][40];
    __shared__ __align__(16) u16 Hb[32][136];
    __shared__ float Ct[32][132];
    const int m0 = blockIdx.x * 32;
    const int tid = threadIdx.x;
    const int lane = tid & 63, w = tid >> 6;
    const int wm = (w >> 1) * 16, wn = (w & 1) * 64;
    const int l15 = lane & 15, l4 = lane >> 4;

    {   // stage X tile [32][256]
        const int row = tid >> 3, c0 = (tid & 7) * 32;
        const u16* ap = xb + (size_t)(m0 + row) * 256 + c0;
        #pragma unroll
        for (int i = 0; i < 4; i++)
            *(int4*)&As[row][c0 + i * 8] = *(const int4*)(ap + i * 8);
    }
    {   // Bs[0] = ew1t k-chunk 0 (pitch 256)
        #pragma unroll
        for (int i = 0; i < 2; i++) {
            int s = tid + i * 256, r = s >> 2, c = (s & 3) * 8;
            *(int4*)&Bs[0][r][c] = *(const int4*)&ew1t[(size_t)r * 256 + c];
        }
    }

    // ---- phase 1: h1 = relu(X @ ew1t^T + eb1), 8 k-steps ----
    fx4 acc[4] = {};
    for (int it = 0; it < 8; it++) {
        const int cur = it & 1;
        int4 br[2];
        __syncthreads();
        if (it < 7) {
            #pragma unroll
            for (int i = 0; i < 2; i++) {
                int s = tid + i * 256, r = s >> 2, c = (s & 3) * 8;
                br[i] = *(const int4*)&ew1t[(size_t)r * 256 + (it + 1) * 32 + c];
            }
        }
        bh8 af = *(const bh8*)&As[wm + l15][it * 32 + l4 * 8];
        #pragma unroll
        for (int nj = 0; nj < 4; nj++) {
            bh8 bf = *(const bh8*)&Bs[cur][wn + nj * 16 + l15][l4 * 8];
            acc[nj] = __builtin_amdgcn_mfma_f32_16x16x32_bf16(af, bf, acc[nj], 0, 0, 0);
        }
        if (it < 7) {
            #pragma unroll
            for (int i = 0; i < 2; i++) {
                int s = tid + i * 256, r = s >> 2, c = (s & 3) * 8;
                *(int4*)&Bs[cur ^ 1][r][c] = br[i];
            }
        }
    }
    // h1 -> Hb (relu+bias); restage Bs[0] = ew2t chunk 0 (last cur was 1)
    #pragma unroll
    for (int nj = 0; nj < 4; nj++) {
        int cl = wn + nj * 16 + l15;
        float bvv = eb1[cl];
        #pragma unroll
        for (int r = 0; r < 4; r++)
            Hb[wm + l4 * 4 + r][cl] = f2bf(fmaxf(acc[nj][r] + bvv, 0.f));
    }
    {
        #pragma unroll
        for (int i = 0; i < 2; i++) {
            int s = tid + i * 256, r = s >> 2, c = (s & 3) * 8;
            *(int4*)&Bs[0][r][c] = *(const int4*)&ew2t[(size_t)r * 128 + c];
        }
    }

    // ---- phase 2: hb = h1 @ ew2t^T + eb2, 4 k-steps ----
    fx4 acc2[4] = {};
    for (int it = 0; it < 4; it++) {
        const int cur = it & 1;
        int4 br[2];
        __syncthreads();
        if (it < 3) {
            #pragma unroll
            for (int i = 0; i < 2; i++) {
                int s = tid + i * 256, r = s >> 2, c = (s & 3) * 8;
                br[i] = *(const int4*)&ew2t[(size_t)r * 128 + (it + 1) * 32 + c];
            }
        }
        bh8 af = *(const bh8*)&Hb[wm + l15][it * 32 + l4 * 8];
        #pragma unroll
        for (int nj = 0; nj < 4; nj++) {
            bh8 bf = *(const bh8*)&Bs[cur][wn + nj * 16 + l15][l4 * 8];
            acc2[nj] = __builtin_amdgcn_mfma_f32_16x16x32_bf16(af, bf, acc2[nj], 0, 0, 0);
        }
        if (it < 3) {
            #pragma unroll
            for (int i = 0; i < 2; i++) {
                int s = tid + i * 256, r = s >> 2, c = (s & 3) * 8;
                *(int4*)&Bs[cur ^ 1][r][c] = br[i];
            }
        }
    }
    // hb -> Hb2 (reuse As space); restage Bs[0] = gwt chunk 0 (last cur 1)
    u16 (*Hb2)[136] = (u16(*)[136])&As[0][0];
    #pragma unroll
    for (int nj = 0; nj < 4; nj++) {
        int cl = wn + nj * 16 + l15;
        float bvv = eb2[cl];
        #pragma unroll
        for (int r = 0; r < 4; r++)
            Hb2[wm + l4 * 4 + r][cl] = f2bf(acc2[nj][r] + bvv);
    }
    {
        #pragma unroll
        for (int i = 0; i < 2; i++) {
            int s = tid + i * 256, r = s >> 2, c = (s & 3) * 8;
            *(int4*)&Bs[0][r][c] = *(const int4*)&gwt[(size_t)r * 128 + c];
        }
    }

    // ---- phase 3: hh = hb @ gwt^T, 4 k-steps ----
    fx4 acc3[4] = {};
    for (int it = 0; it < 4; it++) {
        const int cur = it & 1;
        int4 br[2];
        __syncthreads();
        if (it < 3) {
            #pragma unroll
            for (int i = 0; i < 2; i++) {
                int s = tid + i * 256, r = s >> 2, c = (s & 3) * 8;
                br[i] = *(const int4*)&gwt[(size_t)r * 128 + (it + 1) * 32 + c];
            }
        }
        bh8 af = *(const bh8*)&Hb2[wm + l15][it * 32 + l4 * 8];
        #pragma unroll
        for (int nj = 0; nj < 4; nj++) {
            bh8 bf = *(const bh8*)&Bs[cur][wn + nj * 16 + l15][l4 * 8];
            acc3[nj] = __builtin_amdgcn_mfma_f32_16x16x32_bf16(af, bf, acc3[nj], 0, 0, 0);
        }
        if (it < 3) {
            #pragma unroll
            for (int i = 0; i < 2; i++) {
                int s = tid + i * 256, r = s >> 2, c = (s & 3) * 8;
                *(int4*)&Bs[cur ^ 1][r][c] = br[i];
            }
        }
    }

    // hh -> global bf16 + LDS Ct (f32 for the a-dots)
    #pragma unroll
    for (int nj = 0; nj < 4; nj++) {
        int cl = wn + nj * 16 + l15;
        #pragma unroll
        for (int r = 0; r < 4; r++) {
            int rl = wm + l4 * 4 + r;
            float v = acc3[nj][r];
            hhb[(size_t)(m0 + rl) * 128 + cl] = f2bf(v);
            Ct[rl][cl] = v;
        }
    }
    __syncthreads();

    // per-row a_src/a_dst: 8 threads/row, 16 cols each (4 thr per head)
    const int row = tid >> 3, c0 = (tid & 7) * 16, head = c0 >> 6;
    float ps = 0.f, pd = 0.f;
    #pragma unroll
    for (int j = 0; j < 16; j++) {
        float v = Ct[row][c0 + j];
        int cc = (c0 + j) & 63;
        ps += v * gasrc[head * 64 + cc];
        pd += v * gadst[head * 64 + cc];
    }
    ps += __shfl_xor(ps, 1); pd += __shfl_xor(pd, 1);
    ps += __shfl_xor(ps, 2); pd += __shfl_xor(pd, 2);
    if ((tid & 3) == 0) {
        ansrc[(m0 + row) * 2 + head] = ps;
        andst[(m0 + row) * 2 + head] = pd;
    }

    // ---- fused count_edges (counts pre-zeroed in prep) ----
    for (int i = blockIdx.x * 256 + tid; i < E; i += 128 * 256)
        atomicAdd(&counts[edst[i]], 1);
}

// ------------------------------------------------------------------
// fused FFN: part[z] = relu(A @ W1t^T + b1) @ W2t^T   (BF16 partials)
// grid (64, 8): 64 row-blocks x 8 ff-col slices of 256 (4 chunks of 64)
// ------------------------------------------------------------------
__global__ __launch_bounds__(256) void ffn_fused(
    const u16* __restrict__ A, const u16* __restrict__ W1t,
    const float* __restrict__ b1, const u16* __restrict__ W2t,
    u16* __restrict__ part)
{
    __shared__ __align__(16) u16 Ab[64][136];
    __shared__ __align__(16) u16 Wb[64][136];
    __shared__ __align__(16) u16 Sb[64][72];
    const int m0 = blockIdx.x * 64, z = blockIdx.y;
    const int tid = threadIdx.x;
    const int lane = tid & 63, w = tid >> 6;
    const int wm = (w >> 1) * 32;
    const int wn = (w & 1) * 32;
    const int wn2 = (w & 1) * 64;
    const int l15 = lane & 15, l4 = lane >> 4;
    const int sr = tid >> 2, sc = (tid & 3) * 32;

    {   // stage A: 64 rows x 128 k
        const u16* ap = A + (size_t)(m0 + sr) * 128 + sc;
        #pragma unroll
        for (int i = 0; i < 4; i++)
            *(int4*)&Ab[sr][sc + i * 8] = *(const int4*)(ap + i * 8);
    }

    fx4 acc2[2][4] = {};

    for (int chunk = 0; chunk < 4; chunk++) {
        const int ffbase = z * 256 + chunk * 64;
        __syncthreads();
        {   // stage W1 chunk
            const u16* wp = W1t + (size_t)(ffbase + sr) * 128 + sc;
            #pragma unroll
            for (int i = 0; i < 4; i++)
                *(int4*)&Wb[sr][sc + i * 8] = *(const int4*)(wp + i * 8);
        }
        __syncthreads();

        fx4 s[2][2] = {};
        #pragma unroll
        for (int ks = 0; ks < 4; ks++) {
            bh8 af0 = *(const bh8*)&Ab[wm + l15][ks * 32 + l4 * 8];
            bh8 af1 = *(const bh8*)&Ab[wm + 16 + l15][ks * 32 + l4 * 8];
            bh8 bf0 = *(const bh8*)&Wb[wn + l15][ks * 32 + l4 * 8];
            bh8 bf1 = *(const bh8*)&Wb[wn + 16 + l15][ks * 32 + l4 * 8];
            s[0][0] = __builtin_amdgcn_mfma_f32_16x16x32_bf16(af0, bf0, s[0][0], 0, 0, 0);
            s[0][1] = __builtin_amdgcn_mfma_f32_16x16x32_bf16(af0, bf1, s[0][1], 0, 0, 0);
            s[1][0] = __builtin_amdgcn_mfma_f32_16x16x32_bf16(af1, bf0, s[1][0], 0, 0, 0);
            s[1][1] = __builtin_amdgcn_mfma_f32_16x16x32_bf16(af1, bf1, s[1][1], 0, 0, 0);
        }
        #pragma unroll
        for (int mi = 0; mi < 2; mi++)
            #pragma unroll
            for (int nj = 0; nj < 2; nj++) {
                float bv = b1[ffbase + wn + nj * 16 + l15];
                #pragma unroll
                for (int r = 0; r < 4; r++) {
                    float v = fmaxf(s[mi][nj][r] + bv, 0.f);
                    Sb[wm + mi * 16 + l4 * 4 + r][wn + nj * 16 + l15] = f2bf(v);
                }
            }
        __syncthreads();

        #pragma unroll
        for (int ks = 0; ks < 2; ks++) {
            bh8 af0 = *(const bh8*)&Sb[wm + l15][ks * 32 + l4 * 8];
            bh8 af1 = *(const bh8*)&Sb[wm + 16 + l15][ks * 32 + l4 * 8];
            #pragma unroll
            for (int nj = 0; nj < 4; nj++) {
                bh8 bf = *(const bh8*)&W2t[(size_t)(wn2 + nj * 16 + l15) * 2048 + ffbase + ks * 32 + l4 * 8];
                acc2[0][nj] = __builtin_amdgcn_mfma_f32_16x16x32_bf16(af0, bf, acc2[0][nj], 0, 0, 0);
                acc2[1][nj] = __builtin_amdgcn_mfma_f32_16x16x32_bf16(af1, bf, acc2[1][nj], 0, 0, 0);
            }
        }
    }

    u16* cp = part + (size_t)z * 524288;
    #pragma unroll
    for (int mi = 0; mi < 2; mi++)
        #pragma unroll
        for (int nj = 0; nj < 4; nj++) {
            int colg = wn2 + nj * 16 + l15;
            int rowb = m0 + wm + mi * 16 + l4 * 4;
            #pragma unroll
            for (int r = 0; r < 4; r++)
                cp[(size_t)(rowb + r) * 128 + colg] = f2bf(acc2[mi][nj][r]);
        }
}

// shfl-based scan: per-wave inclusive scan + cross-wave LDS combine
__global__ __launch_bounds__(1024) void scan_kernel(const int* __restrict__ counts,
                                                    int* row_start, int* cursor) {
    __shared__ int wsum[16];
    int tid = threadIdx.x, lane = tid & 63, wv = tid >> 6;
    int b = tid * 4;
    int c0 = counts[b], c1 = counts[b+1], c2 = counts[b+2], c3 = counts[b+3];
    int sum = c0 + c1 + c2 + c3;
    int inc = sum;
    #pragma unroll
    for (int off = 1; off < 64; off <<= 1) {
        int v = __shfl_up(inc, off);
        if (lane >= off) inc += v;
    }
    if (lane == 63) wsum[wv] = inc;
    __syncthreads();
    int base = 0;
    #pragma unroll
    for (int i = 0; i < 16; i++) {
        int v = wsum[i];
        base += (i < wv) ? v : 0;
    }
    int excl = base + inc - sum;
    int r0 = excl, r1 = excl + c0, r2 = r1 + c1, r3 = r2 + c2;
    row_start[b] = r0; row_start[b+1] = r1; row_start[b+2] = r2; row_start[b+3] = r3;
    cursor[b] = r0; cursor[b+1] = r1; cursor[b+2] = r2; cursor[b+3] = r3;
    if (tid == 1023) row_start[4096] = base + inc;
}

__global__ void scatter_edges(const int* __restrict__ src, const int* __restrict__ dst,
                              int* cursor, int* csr_src, int E) {
    int i = blockIdx.x * 256 + threadIdx.x;
    if (i < E) { int pos = atomicAdd(&cursor[dst[i]], 1); csr_src[pos] = src[i]; }
}

// ------------------------------------------------------------------
// GAT aggregate: one block (256 thr) per destination node.
// hh gathered as BF16.
// ------------------------------------------------------------------
__global__ __launch_bounds__(256) void gat_aggregate(
    const int* __restrict__ row_start, const int* __restrict__ csr_src,
    const float* __restrict__ an_src, const float* __restrict__ an_dst,
    const u16* __restrict__ hhb, const float* __restrict__ gbias,
    float* __restrict__ y32, u16* __restrict__ yb)
{
    int n = blockIdx.x, tid = threadIdx.x;
    const int lane = tid & 63, wv = tid >> 6;
    int start = row_start[n], end = row_start[n + 1];
    float ad0 = an_dst[n * 2 + 0], ad1 = an_dst[n * 2 + 1];
    __shared__ float rmx[4][2], rsm[4][2];
    __shared__ float sal0[128], sal1[128], sagg[256];
    __shared__ int sidx[128];

    float mx0 = -1e30f, mx1 = -1e30f;
    for (int i = start + tid; i < end; i += 256) {
        int s = csr_src[i];
        float e0 = an_src[s * 2 + 0] + ad0; e0 = e0 > 0.f ? e0 : 0.2f * e0;
        float e1 = an_src[s * 2 + 1] + ad1; e1 = e1 > 0.f ? e1 : 0.2f * e1;
        mx0 = fmaxf(mx0, e0); mx1 = fmaxf(mx1, e1);
    }
    for (int off = 32; off; off >>= 1) { mx0 = fmaxf(mx0, __shfl_down(mx0, off)); mx1 = fmaxf(mx1, __shfl_down(mx1, off)); }
    if (lane == 0) { rmx[wv][0] = mx0; rmx[wv][1] = mx1; }
    __syncthreads();
    mx0 = fmaxf(fmaxf(rmx[0][0], rmx[1][0]), fmaxf(rmx[2][0], rmx[3][0]));
    mx1 = fmaxf(fmaxf(rmx[0][1], rmx[1][1]), fmaxf(rmx[2][1], rmx[3][1]));

    float den0 = 0.f, den1 = 0.f;
    for (int i = start + tid; i < end; i += 256) {
        int s = csr_src[i];
        float e0 = an_src[s * 2 + 0] + ad0; e0 = e0 > 0.f ? e0 : 0.2f * e0;
        float e1 = an_src[s * 2 + 1] + ad1; e1 = e1 > 0.f ? e1 : 0.2f * e1;
        den0 += __expf(e0 - mx0); den1 += __expf(e1 - mx1);
    }
    for (int off = 32; off; off >>= 1) { den0 += __shfl_down(den0, off); den1 += __shfl_down(den1, off); }
    if (lane == 0) { rsm[wv][0] = den0; rsm[wv][1] = den1; }
    __syncthreads();
    den0 = rsm[0][0] + rsm[1][0] + rsm[2][0] + rsm[3][0];
    den1 = rsm[0][1] + rsm[1][1] + rsm[2][1] + rsm[3][1];
    float rd0 = 1.f / den0, rd1 = 1.f / den1;

    const int grp = tid >> 7, ch = tid & 127, head = ch >> 6;
    float agg = 0.f;
    for (int c0 = start; c0 < end; c0 += 128) {
        int cnt = min(128, end - c0);
        __syncthreads();
        if (tid < cnt) {
            int s = csr_src[c0 + tid];
            float e0 = an_src[s * 2 + 0] + ad0; e0 = e0 > 0.f ? e0 : 0.2f * e0;
            float e1 = an_src[s * 2 + 1] + ad1; e1 = e1 > 0.f ? e1 : 0.2f * e1;
            sal0[tid] = __expf(e0 - mx0) * rd0;
            sal1[tid] = __expf(e1 - mx1) * rd1;
            sidx[tid] = s;
        }
        __syncthreads();
        const float* sal = head ? sal1 : sal0;
        for (int j = grp; j < cnt; j += 2)
            agg += sal[j] * bf2f(hhb[(size_t)sidx[j] * 128 + ch]);
    }
    sagg[tid] = agg;
    __syncthreads();
    if (tid < 128) {
        float v = sagg[tid] + sagg[tid + 128] + gbias[tid];
        y32[(size_t)n * 128 + tid] = v;
        yb[(size_t)n * 128 + tid] = f2bf(v);
    }
}

// ------------------------------------------------------------------
// flash attention partial: QBLK=128 q-rows/block, grid (32, NH, 4
// chunks of 1024 keys) = 512 blocks (one scheduling wave at 4/CU).
// O partials written BF16 (cvt_pk).
// ------------------------------------------------------------------
__global__ __launch_bounds__(256) void flash_attn_part(
    const u16* __restrict__ q, const u16* __restrict__ k,
    const u16* __restrict__ vt, u16* __restrict__ po,
    float* __restrict__ pm, float* __restrict__ pl)
{
    __shared__ __align__(16) u16 Kb[2][64][40];
    __shared__ __align__(16) u16 Vb[2][32][72];
    __shared__ __align__(16) u16 Ps[4][32][72];
    const int q0 = blockIdx.x * 128, h = blockIdx.y, ch = blockIdx.z;
    const int tid = threadIdx.x;
    const int w = tid >> 6, lane = tid & 63, l15 = lane & 15, l4 = lane >> 4;

    bh8 qf0 = *(const bh8*)&q[(size_t)(q0 + w * 32 + l15) * 256 + h * 32 + l4 * 8];
    bh8 qf1 = *(const bh8*)&q[(size_t)(q0 + w * 32 + 16 + l15) * 256 + h * 32 + l4 * 8];

    const int skey = tid >> 2, sds = (tid & 3) * 8;   // K staging: 64 keys x 32 d
    const int svd = tid >> 3, svk = (tid & 7) * 8;    // V staging: 32 d x 64 keys
    const u16* kgp = &k[(size_t)(ch * 1024 + skey) * 256 + h * 32 + sds];
    const u16* vgp = &vt[(size_t)(h * 32 + svd) * 4096 + ch * 1024 + svk];

    fx4 o00 = {0,0,0,0}, o01 = {0,0,0,0}, o10 = {0,0,0,0}, o11 = {0,0,0,0};
    float M0 = -1e30f, L0 = 0.f, M1 = -1e30f, L1 = 0.f;

    *(int4*)&Kb[0][skey][sds] = *(const int4*)kgp;
    *(int4*)&Vb[0][svd][svk] = *(const int4*)vgp;

    for (int ti = 0; ti < 16; ti++) {
        const int cur = ti & 1;
        int4 kr, vr;
        __syncthreads();
        if (ti < 15) {   // issue next-tile loads AFTER barrier; compute hides latency
            kr = *(const int4*)(kgp + (size_t)(ti + 1) * 64 * 256);
            vr = *(const int4*)(vgp + (ti + 1) * 64);
        }

        fx4 s0[4], s1[4];
        #pragma unroll
        for (int sub = 0; sub < 4; sub++) {
            bh8 kf = *(const bh8*)&Kb[cur][sub * 16 + l15][l4 * 8];
            fx4 z = {0,0,0,0};
            s0[sub] = __builtin_amdgcn_mfma_f32_16x16x32_bf16(kf, qf0, z, 0, 0, 0);
            s1[sub] = __builtin_amdgcn_mfma_f32_16x16x32_bf16(kf, qf1, z, 0, 0, 0);
        }
        // ---- softmax half 0 ----
        {
            float t0 = fmaxf(fmaxf(s0[0][0], s0[0][1]), s0[0][2]);
            float t1 = fmaxf(fmaxf(s0[0][3], s0[1][0]), s0[1][1]);
            float t2 = fmaxf(fmaxf(s0[1][2], s0[1][3]), s0[2][0]);
            float t3 = fmaxf(fmaxf(s0[2][1], s0[2][2]), s0[2][3]);
            float t4 = fmaxf(fmaxf(s0[3][0], s0[3][1]), s0[3][2]);
            float pmax = fmaxf(fmaxf(fmaxf(t0, t1), t2), fmaxf(fmaxf(t3, t4), s0[3][3]));
            pmax = fmaxf(pmax, __shfl_xor(pmax, 16));
            pmax = fmaxf(pmax, __shfl_xor(pmax, 32));
            if (!__all(pmax - M0 <= 8.0f)) {
                float f = __builtin_amdgcn_exp2f(M0 - pmax);
                M0 = pmax;
                o00 *= f; o01 *= f; L0 *= f;
            }
            #pragma unroll
            for (int sub = 0; sub < 4; sub++)
                #pragma unroll
                for (int r = 0; r < 4; r++)
                    s0[sub][r] = __builtin_amdgcn_exp2f(s0[sub][r] - M0);
            float ss0 = (s0[0][0] + s0[0][1]) + (s0[0][2] + s0[0][3]);
            float ss1 = (s0[1][0] + s0[1][1]) + (s0[1][2] + s0[1][3]);
            float ss2 = (s0[2][0] + s0[2][1]) + (s0[2][2] + s0[2][3]);
            float ss3 = (s0[3][0] + s0[3][1]) + (s0[3][2] + s0[3][3]);
            float lsum = (ss0 + ss1) + (ss2 + ss3);
            lsum += __shfl_xor(lsum, 16);
            lsum += __shfl_xor(lsum, 32);
            L0 += lsum;
        }
        // ---- softmax half 1 ----
        {
            float t0 = fmaxf(fmaxf(s1[0][0], s1[0][1]), s1[0][2]);
            float t1 = fmaxf(fmaxf(s1[0][3], s1[1][0]), s1[1][1]);
            float t2 = fmaxf(fmaxf(s1[1][2], s1[1][3]), s1[2][0]);
            float t3 = fmaxf(fmaxf(s1[2][1], s1[2][2]), s1[2][3]);
            float t4 = fmaxf(fmaxf(s1[3][0], s1[3][1]), s1[3][2]);
            float pmax = fmaxf(fmaxf(fmaxf(t0, t1), t2), fmaxf(fmaxf(t3, t4), s1[3][3]));
            pmax = fmaxf(pmax, __shfl_xor(pmax, 16));
            pmax = fmaxf(pmax, __shfl_xor(pmax, 32));
            if (!__all(pmax - M1 <= 8.0f)) {
                float f = __builtin_amdgcn_exp2f(M1 - pmax);
                M1 = pmax;
                o10 *= f; o11 *= f; L1 *= f;
            }
            #pragma unroll
            for (int sub = 0; sub < 4; sub++)
                #pragma unroll
                for (int r = 0; r < 4; r++)
                    s1[sub][r] = __builtin_amdgcn_exp2f(s1[sub][r] - M1);
            float ss0 = (s1[0][0] + s1[0][1]) + (s1[0][2] + s1[0][3]);
            float ss1 = (s1[1][0] + s1[1][1]) + (s1[1][2] + s1[1][3]);
            float ss2 = (s1[2][0] + s1[2][1]) + (s1[2][2] + s1[2][3]);
            float ss3 = (s1[3][0] + s1[3][1]) + (s1[3][2] + s1[3][3]);
            float lsum = (ss0 + ss1) + (ss2 + ss3);
            lsum += __shfl_xor(lsum, 16);
            lsum += __shfl_xor(lsum, 32);
            L1 += lsum;
        }

        // pack P^T into Ps[w][q][key] (wave-private)
        #pragma unroll
        for (int sub = 0; sub < 4; sub++) {
            u32x2 pk0 = { cvtpk(s0[sub][0], s0[sub][1]), cvtpk(s0[sub][2], s0[sub][3]) };
            *(u32x2*)&Ps[w][l15][sub * 16 + l4 * 4] = pk0;
            u32x2 pk1 = { cvtpk(s1[sub][0], s1[sub][1]), cvtpk(s1[sub][2], s1[sub][3]) };
            *(u32x2*)&Ps[w][16 + l15][sub * 16 + l4 * 4] = pk1;
        }

        // PV: O^T += V^T @ P^T (both halves)
        #pragma unroll
        for (int kc = 0; kc < 2; kc++) {
            bh8 bfA = *(const bh8*)&Ps[w][l15][kc * 32 + l4 * 8];
            bh8 bfB = *(const bh8*)&Ps[w][16 + l15][kc * 32 + l4 * 8];
            bh8 af0 = *(const bh8*)&Vb[cur][l15][kc * 32 + l4 * 8];
            bh8 af1 = *(const bh8*)&Vb[cur][16 + l15][kc * 32 + l4 * 8];
            o00 = __builtin_amdgcn_mfma_f32_16x16x32_bf16(af0, bfA, o00, 0, 0, 0);
            o01 = __builtin_amdgcn_mfma_f32_16x16x32_bf16(af1, bfA, o01, 0, 0, 0);
            o10 = __builtin_amdgcn_mfma_f32_16x16x32_bf16(af0, bfB, o10, 0, 0, 0);
            o11 = __builtin_amdgcn_mfma_f32_16x16x32_bf16(af1, bfB, o11, 0, 0, 0);
        }

        if (ti < 15) {   // write next tile (vmcnt waits land here, after compute)
            *(int4*)&Kb[cur ^ 1][skey][sds] = kr;
            *(int4*)&Vb[cur ^ 1][svd][svk] = vr;
        }
    }
    const int base = (blockIdx.x * 4 + h) * 4 + ch;
    const int qA = w * 32 + l15, qB = qA + 16;
    {
        u32x2 wA0 = { cvtpk(o00[0], o00[1]), cvtpk(o00[2], o00[3]) };
        u32x2 wA1 = { cvtpk(o01[0], o01[1]), cvtpk(o01[2], o01[3]) };
        *(u32x2*)&po[(size_t)(base * 128 + qA) * 32 + l4 * 4]      = wA0;
        *(u32x2*)&po[(size_t)(base * 128 + qA) * 32 + 16 + l4 * 4] = wA1;
        u32x2 wB0 = { cvtpk(o10[0], o10[1]), cvtpk(o10[2], o10[3]) };
        u32x2 wB1 = { cvtpk(o11[0], o11[1]), cvtpk(o11[2], o11[3]) };
        *(u32x2*)&po[(size_t)(base * 128 + qB) * 32 + l4 * 4]      = wB0;
        *(u32x2*)&po[(size_t)(base * 128 + qB) * 32 + 16 + l4 * 4] = wB1;
    }
    if (l4 == 0) {
        pm[base * 128 + qA] = M0; pl[base * 128 + qA] = L0;
        pm[base * 128 + qB] = M1; pl[base * 128 + qB] = L1;
    }
}

// ------------------------------------------------------------------
// fused combine(4 KV-chunks, bf16 partials) + O-proj + residual + LN.
// ------------------------------------------------------------------
__global__ __launch_bounds__(256) void oproj_cln(
    const u16* __restrict__ po, const float* __restrict__ pm,
    const float* __restrict__ pl, const u16* __restrict__ Bt,
    const float* __restrict__ bias, const float* __restrict__ g,
    const float* __restrict__ b,
    float* __restrict__ y32, u16* __restrict__ yb)
{
    __shared__ __align__(16) u16 Ab[32][136];
    __shared__ __align__(16) u16 Bs[2][128][40];
    __shared__ float Ct[32][132];
    const int m0 = blockIdx.x * 32;
    const int tid = threadIdx.x;
    const int lane = tid & 63, w = tid >> 6;
    const int wm = (w >> 1) * 16, wn = (w & 1) * 64;
    const int l15 = lane & 15, l4 = lane >> 4;

    {   // combine 4 KV-chunk partials into A tile (bf16)
        const int row = tid >> 3, c0 = (tid & 7) * 16;
        const int gr = m0 + row, qb = gr >> 7, r1 = gr & 127, h = c0 >> 5;
        const int rb = (qb * 4 + h) * 4;
        float ms = -1e30f;
        float mv[4];
        #pragma unroll
        for (int c = 0; c < 4; c++) { mv[c] = pm[(rb + c) * 128 + r1]; ms = fmaxf(ms, mv[c]); }
        float wc[4], lsum = 0.f;
        #pragma unroll
        for (int c = 0; c < 4; c++) {
            wc[c] = __builtin_amdgcn_exp2f(mv[c] - ms);
            lsum += wc[c] * pl[(rb + c) * 128 + r1];
        }
        float rl = 1.f / lsum;
        const int cb = c0 & 31;
        float o[16] = {};
        #pragma unroll
        for (int c = 0; c < 4; c++) {
            const u16* pp = po + ((size_t)((rb + c) * 128 + r1)) * 32 + cb;
            s4 v0 = *(const s4*)pp;
            s4 v1 = *(const s4*)(pp + 4);
            s4 v2 = *(const s4*)(pp + 8);
            s4 v3 = *(const s4*)(pp + 12);
            #pragma unroll
            for (int j = 0; j < 4; j++) {
                o[j]      += wc[c] * bf2f((u16)v0[j]);
                o[4 + j]  += wc[c] * bf2f((u16)v1[j]);
                o[8 + j]  += wc[c] * bf2f((u16)v2[j]);
                o[12 + j] += wc[c] * bf2f((u16)v3[j]);
            }
        }
        #pragma unroll
        for (int j = 0; j < 16; j++)
            Ab[row][c0 + j] = f2bf(o[j] * rl);
    }

    {   // stage Bs[0]
        const int brow = tid >> 2, bkq = (tid & 3) * 8;
        *(int4*)&Bs[0][brow][bkq]      = *(const int4*)&Bt[(size_t)brow * 128 + bkq];
        *(int4*)&Bs[0][brow + 64][bkq] = *(const int4*)&Bt[(size_t)(brow + 64) * 128 + bkq];
    }

    fx4 acc[4] = {};
    const int brow = tid >> 2, bkq = (tid & 3) * 8;
    for (int it = 0; it < 4; it++) {
        const int cur = it & 1;
        int4 br0, br1;
        __syncthreads();
        if (it < 3) {
            br0 = *(const int4*)&Bt[(size_t)brow * 128 + (it + 1) * 32 + bkq];
            br1 = *(const int4*)&Bt[(size_t)(brow + 64) * 128 + (it + 1) * 32 + bkq];
        }
        bh8 af = *(const bh8*)&Ab[wm + l15][it * 32 + l4 * 8];
        #pragma unroll
        for (int nj = 0; nj < 4; nj++) {
            bh8 bf = *(const bh8*)&Bs[cur][wn + nj * 16 + l15][l4 * 8];
            acc[nj] = __builtin_amdgcn_mfma_f32_16x16x32_bf16(af, bf, acc[nj], 0, 0, 0);
        }
        if (it < 3) {
            *(int4*)&Bs[cur ^ 1][brow][bkq]      = br0;
            *(int4*)&Bs[cur ^ 1][brow + 64][bkq] = br1;
        }
    }

    #pragma unroll
    for (int nj = 0; nj < 4; nj++) {
        int cl = wn + nj * 16 + l15;
        float bvv = bias[cl];
        #pragma unroll
        for (int r = 0; r < 4; r++) {
            int rl = wm + l4 * 4 + r;
            Ct[rl][cl] = acc[nj][r] + bvv + y32[(size_t)(m0 + rl) * 128 + cl];
        }
    }
    __syncthreads();

    const int row = tid >> 3, c0 = (tid & 7) * 16;
    float s1 = 0.f, s2 = 0.f;
    #pragma unroll
    for (int j = 0; j < 16; j++) { float v = Ct[row][c0 + j]; s1 += v; s2 += v * v; }
    #pragma unroll
    for (int off = 1; off < 8; off <<= 1) { s1 += __shfl_xor(s1, off); s2 += __shfl_xor(s2, off); }
    float mean = s1 * (1.f / 128.f);
    float var = s2 * (1.f / 128.f) - mean * mean;
    float rstd = rsqrtf(var + 1e-5f);
    #pragma unroll
    for (int j = 0; j < 16; j++) {
        int col = c0 + j;
        float o = (Ct[row][col] - mean) * rstd * g[col] + b[col];
        y32[(size_t)(m0 + row) * 128 + col] = o;
        yb[(size_t)(m0 + row) * 128 + col] = f2bf(o);
    }
}

// ------------------------------------------------------------------
// residual add + nz split-K bf16 partials + bias + LayerNorm
// ------------------------------------------------------------------
__global__ __launch_bounds__(128) void add_ln_p(
    const float* __restrict__ y, const u16* __restrict__ part, int nz,
    const float* __restrict__ bias,
    const float* __restrict__ g, const float* __restrict__ b,
    float* __restrict__ out32, u16* __restrict__ outb)
{
    int n = blockIdx.x, tid = threadIdx.x;
    float v = y[(size_t)n * 128 + tid] + bias[tid];
    for (int z = 0; z < nz; z++) v += bf2f(part[(size_t)z * 524288 + n * 128 + tid]);
    float sacc = v;
    for (int off = 32; off; off >>= 1) sacc += __shfl_down(sacc, off);
    __shared__ float sm[2], sv[2];
    if ((tid & 63) == 0) sm[tid >> 6] = sacc;
    __syncthreads();
    float mean = (sm[0] + sm[1]) * (1.f / 128.f);
    float d = v - mean;
    float qacc = d * d;
    for (int off = 32; off; off >>= 1) qacc += __shfl_down(qacc, off);
    if ((tid & 63) == 0) sv[tid >> 6] = qacc;
    __syncthreads();
    float var = (sv[0] + sv[1]) * (1.f / 128.f);
    float o = d * rsqrtf(var + 1e-5f) * g[tid] + b[tid];
    out32[(size_t)n * 128 + tid] = o;
    outb[(size_t)n * 128 + tid] = f2bf(o);
}

// ------------------------------------------------------------------
extern "C" void kernel_launch(void* const* d_in, const int* in_sizes, int n_in,
                              void* d_out, int out_size, void* d_ws, size_t ws_size,
                              hipStream_t stream)
{
    const float* x     = (const float*)d_in[0];
    const int*   ei    = (const int*)  d_in[1];
    const float* ew1   = (const float*)d_in[2];
    const float* eb1   = (const float*)d_in[3];
    const float* ew2   = (const float*)d_in[4];
    const float* eb2   = (const float*)d_in[5];
    const float* gw    = (const float*)d_in[6];
    const float* gasrc = (const float*)d_in[7];
    const float* gadst = (const float*)d_in[8];
    const float* gbias = (const float*)d_in[9];
    const float* wq    = (const float*)d_in[10];
    const float* bq    = (const float*)d_in[11];
    const float* wk    = (const float*)d_in[12];
    const float* bk    = (const float*)d_in[13];
    const float* wv    = (const float*)d_in[14];
    const float* bv    = (const float*)d_in[15];
    const float* wo    = (const float*)d_in[16];
    const float* bo    = (const float*)d_in[17];
    const float* ln1g  = (const float*)d_in[18];
    const float* ln1b  = (const float*)d_in[19];
    const float* ln2g  = (const float*)d_in[20];
    const float* ln2b  = (const float*)d_in[21];
    const float* w1    = (const float*)d_in[22];
    const float* b1    = (const float*)d_in[23];
    const float* w2    = (const float*)d_in[24];
    const float* b2    = (const float*)d_in[25];

    const int E = in_sizes[1] / 2;
    const int* esrc = ei;
    const int* edst = ei + E;

    char* p = (char*)d_ws;
    auto alloc = [&](size_t bytes) -> void* {
        void* r = (void*)p;
        p += (bytes + 255) & ~(size_t)255;
        return r;
    };
    u16* xb    = (u16*)alloc(4096 * 256 * 2);
    u16* ew1t  = (u16*)alloc(128 * 256 * 2);
    u16* ew2t  = (u16*)alloc(128 * 128 * 2);
    u16* gwt   = (u16*)alloc(128 * 128 * 2);
    u16* wqkvt = (u16*)alloc(2 * 384 * 128 * 2);
    float* bqkv = (float*)alloc(2 * 384 * 4);
    u16* wot   = (u16*)alloc(2 * 128 * 128 * 2);
    u16* w1t   = (u16*)alloc(2 * 2048 * 128 * 2);
    u16* w2t   = (u16*)alloc(2 * 128 * 2048 * 2);
    u16* hhb   = (u16*)alloc(4096 * 128 * 2);
    float* ansrc = (float*)alloc(4096 * 2 * 4);
    float* andst = (float*)alloc(4096 * 2 * 4);
    int* counts    = (int*)alloc(4096 * 4);
    int* row_start = (int*)alloc(4097 * 4);
    int* cursor    = (int*)alloc(4096 * 4);
    int* csr_src   = (int*)alloc((size_t)E * 4);
    float* y32 = (float*)alloc(4096 * 128 * 4);
    u16* yb    = (u16*)alloc(4096 * 128 * 2);
    u16* qkvb  = (u16*)alloc((size_t)4096 * 256 * 2);   // Q,K only (pitch 256)
    u16* vtb   = (u16*)alloc(4096 * 128 * 2);           // V transposed [128][4096]
    u16* po    = (u16*)alloc((size_t)32 * 4 * 4 * 128 * 32 * 2);
    float* pm  = (float*)alloc(32 * 4 * 4 * 128 * 4);
    float* pl  = (float*)alloc(32 * 4 * 4 * 128 * 4);
    u16* ffpart = (u16*)alloc((size_t)8 * 4096 * 128 * 2);

    // ---- prep (includes counts zeroing) ----
    prep_kernel<<<449, 256, 0, stream>>>(x, ew1, ew2, gw, wq, wk, wv, wo, w1, w2,
                                         bq, bk, bv,
                                         xb, ew1t, ew2t, gwt, wqkvt, bqkv, wot, w1t, w2t,
                                         counts);

    // ---- fused encoder + GAT front-end + edge counting ----
    encoder_gat<<<128, 256, 0, stream>>>(xb, ew1t, eb1, ew2t, eb2, gwt,
                                         gasrc, gadst, hhb, ansrc, andst, counts, edst, E);
    scan_kernel<<<1, 1024, 0, stream>>>(counts, row_start, cursor);
    scatter_edges<<<(E + 255) / 256, 256, 0, stream>>>(esrc, edst, cursor, csr_src, E);
    gat_aggregate<<<4096, 256, 0, stream>>>(row_start, csr_src, ansrc, andst, hhb, gbias, y32, yb);

    // ---- transformer layers ----
    for (int l = 0; l < 2; l++) {
        gemm_bf16<<<dim3(64, 6), 256, 0, stream>>>(yb, wqkvt + l * 49152, bqkv + l * 384, nullptr, qkvb, nullptr, vtb, 4096, 384, 128, 0, 128, 256);
        flash_attn_part<<<dim3(32, 4, 4), 256, 0, stream>>>(qkvb, qkvb + 128, vtb, po, pm, pl);
        oproj_cln<<<128, 256, 0, stream>>>(po, pm, pl, wot + l * 16384, bo + l * 128, ln1g + l * 128, ln1b + l * 128, y32, yb);
        ffn_fused<<<dim3(64, 8), 256, 0, stream>>>(yb, w1t + (size_t)l * 262144, b1 + l * 2048, w2t + (size_t)l * 262144, ffpart);
        float* outp = (l == 1) ? (float*)d_out : y32;
        add_ln_p<<<4096, 128, 0, stream>>>(y32, ffpart, 8, b2 + l * 128, ln2g + l * 128, ln2b + l * 128, outp, yb);
    }
}

// Round 21
// 174.469 us; speedup vs baseline: 1.0189x; 1.0189x over previous
//
#include <hip/hip_runtime.h>

typedef unsigned short u16;
typedef unsigned int u32;
typedef __attribute__((ext_vector_type(8))) short bh8;   // 8 x bf16 raw bits
typedef __attribute__((ext_vector_type(4))) float fx4;
typedef __attribute__((ext_vector_type(4))) short s4;
typedef __attribute__((ext_vector_type(2))) unsigned int u32x2;

#define QS 0.2550437194342803f   /* (1/sqrt(32)) * log2(e) */

__device__ __forceinline__ u16 f2bf(float f) {
    unsigned u = __float_as_uint(f);
    u += 0x7fffu + ((u >> 16) & 1u);   // round-to-nearest-even
    return (u16)(u >> 16);
}

__device__ __forceinline__ float bf2f(u16 b) {
    return __uint_as_float((u32)b << 16);
}

__device__ __forceinline__ u32 cvtpk(float lo, float hi) {
    u32 r;
    asm("v_cvt_pk_bf16_f32 %0, %1, %2" : "=v"(r) : "v"(lo), "v"(hi));
    return r;
}

// ------------------------------------------------------------------
// prep: x -> bf16; counts zeroed; weights transposed via tiled 64x64
// LDS transpose; fused QKV weight/bias with Q pre-scaled by QS.
// grid = 128 (x) + 16 (counts) + 1 (bias) + 304 tiles = 449 blocks
// ------------------------------------------------------------------
__global__ __launch_bounds__(256) void prep_kernel(
    const float* x, const float* ew1, const float* ew2, const float* gw,
    const float* wq, const float* wk, const float* wv, const float* wo,
    const float* w1, const float* w2,
    const float* bq, const float* bk, const float* bv,
    u16* xb, u16* ew1t, u16* ew2t, u16* gwt,
    u16* wqkvt, float* bqkv, u16* wot, u16* w1t, u16* w2t,
    int* counts)
{
    __shared__ u16 tile[64 * 65];
    int bid = blockIdx.x;
    const int t = threadIdx.x;

    if (bid < 128) {   // x convert: 1M floats
        const float4* x4 = (const float4*)x;
        s4* o4 = (s4*)xb;
        #pragma unroll
        for (int i = 0; i < 8; i++) {
            int fi = bid * 2048 + i * 256 + t;
            float4 v = x4[fi];
            s4 o = { (short)f2bf(v.x), (short)f2bf(v.y), (short)f2bf(v.z), (short)f2bf(v.w) };
            o4[fi] = o;
        }
        return;
    }
    bid -= 128;
    if (bid < 16) {    // zero counts[4096]
        counts[bid * 256 + t] = 0;
        return;
    }
    bid -= 16;
    if (bid < 1) {     // bqkv [2][384]
        for (int idx = t; idx < 768; idx += 256) {
            int l = idx / 384, n = idx % 384;
            float v;
            if (n < 128)      v = bq[l * 128 + n] * QS;
            else if (n < 256) v = bk[l * 128 + n - 128];
            else              v = bv[l * 128 + n - 256];
            bqkv[idx] = v;
        }
        return;
    }
    bid -= 1;

    const float* src; u16* dst; int R, C, tr, tc; float sc = 1.f;
    if (bid < 8)            { src = ew1; dst = ew1t; R = 256; C = 128; tr = bid >> 1; tc = bid & 1; }
    else if ((bid -= 8) < 4)  { src = ew2; dst = ew2t; R = 128; C = 128; tr = bid >> 1; tc = bid & 1; }
    else if ((bid -= 4) < 4)  { src = gw;  dst = gwt;  R = 128; C = 128; tr = bid >> 1; tc = bid & 1; }
    else if ((bid -= 4) < 24) {
        int l = bid / 12, r2 = bid % 12, which = r2 >> 2, i = r2 & 3;
        R = 128; C = 128; tr = i >> 1; tc = i & 1;
        if (which == 0)      { src = wq + l * 16384; dst = wqkvt + l * 49152;         sc = QS; }
        else if (which == 1) { src = wk + l * 16384; dst = wqkvt + l * 49152 + 16384; }
        else                 { src = wv + l * 16384; dst = wqkvt + l * 49152 + 32768; }
    }
    else if ((bid -= 24) < 8)   { int l = bid >> 2, i = bid & 3;  src = wo + l * 16384; dst = wot + l * 16384; R = 128; C = 128; tr = i >> 1; tc = i & 1; }
    else if ((bid -= 8) < 128)  { int l = bid >> 6, i = bid & 63; src = w1 + (size_t)l * 262144; dst = w1t + (size_t)l * 262144; R = 128;  C = 2048; tr = i & 1;  tc = i >> 1; }
    else { bid -= 128;            int l = bid >> 6, i = bid & 63; src = w2 + (size_t)l * 262144; dst = w2t + (size_t)l * 262144; R = 2048; C = 128;  tr = i >> 1; tc = i & 1; }

    const int r = t >> 2, cs = (t & 3) * 16;
    const float* sp = src + (size_t)(tr * 64 + r) * C + tc * 64 + cs;
    #pragma unroll
    for (int j = 0; j < 16; j++) tile[r * 65 + cs + j] = f2bf(sp[j] * sc);
    __syncthreads();
    u16* dp = dst + (size_t)(tc * 64 + r) * R + tr * 64 + cs;
    #pragma unroll
    for (int j = 0; j < 16; j++) dp[j] = tile[(cs + j) * 65 + r];
}

// ------------------------------------------------------------------
// staged bf16 MFMA GEMM (64x64 tile) — used for QKV
// ------------------------------------------------------------------
__global__ __launch_bounds__(256) void gemm_bf16(
    const u16* __restrict__ A, const u16* __restrict__ Bt,
    const float* __restrict__ bias,
    float* __restrict__ Cf, u16* __restrict__ Cb, float* __restrict__ Cpart,
    u16* __restrict__ Cvt,
    int M, int N, int K, int relu, int kchunk, int ldc)
{
    __shared__ __align__(16) u16 As[2][64][40];
    __shared__ __align__(16) u16 Bs[2][64][40];
    const int m0 = blockIdx.x * 64, n0 = blockIdx.y * 64, z = blockIdx.z;
    const int tid = threadIdx.x;
    const int lane = tid & 63, w = tid >> 6;
    const int wm = (w >> 1) * 32, wn = (w & 1) * 32;
    const int l15 = lane & 15, l4 = lane >> 4;
    const int srow = tid >> 2, skq = (tid & 3) * 8;
    const int k0 = z * kchunk;

    const u16* Ap = A + (size_t)(m0 + srow) * K + k0 + skq;
    const u16* Bp = Bt + (size_t)(n0 + srow) * K + k0 + skq;

    fx4 acc00 = {0,0,0,0}, acc01 = {0,0,0,0}, acc10 = {0,0,0,0}, acc11 = {0,0,0,0};

    *(int4*)&As[0][srow][skq] = *(const int4*)Ap;
    *(int4*)&Bs[0][srow][skq] = *(const int4*)Bp;

    const int niter = kchunk >> 5;
    for (int it = 0; it < niter; it++) {
        const int cur = it & 1;
        int4 ar, br;
        __syncthreads();
        if (it + 1 < niter) {
            ar = *(const int4*)(Ap + (it + 1) * 32);
            br = *(const int4*)(Bp + (it + 1) * 32);
        }
        bh8 a0 = *(const bh8*)&As[cur][wm + l15][l4 * 8];
        bh8 a1 = *(const bh8*)&As[cur][wm + 16 + l15][l4 * 8];
        bh8 b0 = *(const bh8*)&Bs[cur][wn + l15][l4 * 8];
        bh8 b1 = *(const bh8*)&Bs[cur][wn + 16 + l15][l4 * 8];
        acc00 = __builtin_amdgcn_mfma_f32_16x16x32_bf16(a0, b0, acc00, 0, 0, 0);
        acc01 = __builtin_amdgcn_mfma_f32_16x16x32_bf16(a0, b1, acc01, 0, 0, 0);
        acc10 = __builtin_amdgcn_mfma_f32_16x16x32_bf16(a1, b0, acc10, 0, 0, 0);
        acc11 = __builtin_amdgcn_mfma_f32_16x16x32_bf16(a1, b1, acc11, 0, 0, 0);
        if (it + 1 < niter) {
            *(int4*)&As[cur ^ 1][srow][skq] = ar;
            *(int4*)&Bs[cur ^ 1][srow][skq] = br;
        }
    }

    fx4* accs[2][2] = {{&acc00, &acc01}, {&acc10, &acc11}};
    #pragma unroll
    for (int i = 0; i < 2; i++)
        #pragma unroll
        for (int j = 0; j < 2; j++) {
            int colg = n0 + wn + j * 16 + l15;
            int rowb = m0 + wm + i * 16 + l4 * 4;
            if (Cpart) {
                float* cp = Cpart + (size_t)z * M * N;
                #pragma unroll
                for (int r = 0; r < 4; r++)
                    cp[(size_t)(rowb + r) * N + colg] = (*accs[i][j])[r];
                continue;
            }
            float bvv = bias ? bias[colg] : 0.f;
            float vals[4];
            #pragma unroll
            for (int r = 0; r < 4; r++) {
                float v = (*accs[i][j])[r] + bvv;
                vals[r] = relu ? fmaxf(v, 0.f) : v;
            }
            if (Cvt && colg >= 256) {
                s4 pk = { (short)f2bf(vals[0]), (short)f2bf(vals[1]),
                          (short)f2bf(vals[2]), (short)f2bf(vals[3]) };
                *(s4*)&Cvt[(size_t)(colg - 256) * 4096 + rowb] = pk;
            } else {
                #pragma unroll
                for (int r = 0; r < 4; r++) {
                    if (Cf) Cf[(size_t)(rowb + r) * ldc + colg] = vals[r];
                    if (Cb) Cb[(size_t)(rowb + r) * ldc + colg] = f2bf(vals[r]);
                }
            }
        }
}

// ------------------------------------------------------------------
// FULL encoder + GAT front-end fusion + edge counting:
// h1 = relu(x @ ew1t^T + eb1); hb = h1 @ ew2t^T + eb2 (LDS only);
// hh = hb @ gwt^T -> global BF16; a_src/a_dst dots; then grid-stride
// count_edges atomics (counts pre-zeroed in prep).
// grid 128 x 256 thr; BM=32, BN=128.
// ------------------------------------------------------------------
__global__ __launch_bounds__(256) void encoder_gat(
    const u16* __restrict__ xb, const u16* __restrict__ ew1t,
    const float* __restrict__ eb1,
    const u16* __restrict__ ew2t, const float* __restrict__ eb2,
    const u16* __restrict__ gwt,
    const float* __restrict__ gasrc, const float* __restrict__ gadst,
    u16* __restrict__ hhb, float* __restrict__ ansrc,
    float* __restrict__ andst, int* __restrict__ counts,
    const int* __restrict__ edst, int E)
{
    __shared__ __align__(16) u16 As[32][264];
    __shared__ __align__(16) u16 Bs[2][128][40];
    __shared__ __align__(16) u16 Hb[32][136];
    __shared__ float Ct[32][132];
    const int m0 = blockIdx.x * 32;
    const int tid = threadIdx.x;
    const int lane = tid & 63, w = tid >> 6;
    const int wm = (w >> 1) * 16, wn = (w & 1) * 64;
    const int l15 = lane & 15, l4 = lane >> 4;

    {   // stage X tile [32][256]
        const int row = tid >> 3, c0 = (tid & 7) * 32;
        const u16* ap = xb + (size_t)(m0 + row) * 256 + c0;
        #pragma unroll
        for (int i = 0; i < 4; i++)
            *(int4*)&As[row][c0 + i * 8] = *(const int4*)(ap + i * 8);
    }
    {   // Bs[0] = ew1t k-chunk 0 (pitch 256)
        #pragma unroll
        for (int i = 0; i < 2; i++) {
            int s = tid + i * 256, r = s >> 2, c = (s & 3) * 8;
            *(int4*)&Bs[0][r][c] = *(const int4*)&ew1t[(size_t)r * 256 + c];
        }
    }

    // ---- phase 1: h1 = relu(X @ ew1t^T + eb1), 8 k-steps ----
    fx4 acc[4] = {};
    for (int it = 0; it < 8; it++) {
        const int cur = it & 1;
        int4 br[2];
        __syncthreads();
        if (it < 7) {
            #pragma unroll
            for (int i = 0; i < 2; i++) {
                int s = tid + i * 256, r = s >> 2, c = (s & 3) * 8;
                br[i] = *(const int4*)&ew1t[(size_t)r * 256 + (it + 1) * 32 + c];
            }
        }
        bh8 af = *(const bh8*)&As[wm + l15][it * 32 + l4 * 8];
        #pragma unroll
        for (int nj = 0; nj < 4; nj++) {
            bh8 bf = *(const bh8*)&Bs[cur][wn + nj * 16 + l15][l4 * 8];
            acc[nj] = __builtin_amdgcn_mfma_f32_16x16x32_bf16(af, bf, acc[nj], 0, 0, 0);
        }
        if (it < 7) {
            #pragma unroll
            for (int i = 0; i < 2; i++) {
                int s = tid + i * 256, r = s >> 2, c = (s & 3) * 8;
                *(int4*)&Bs[cur ^ 1][r][c] = br[i];
            }
        }
    }
    // h1 -> Hb (relu+bias); restage Bs[0] = ew2t chunk 0 (last cur was 1)
    #pragma unroll
    for (int nj = 0; nj < 4; nj++) {
        int cl = wn + nj * 16 + l15;
        float bvv = eb1[cl];
        #pragma unroll
        for (int r = 0; r < 4; r++)
            Hb[wm + l4 * 4 + r][cl] = f2bf(fmaxf(acc[nj][r] + bvv, 0.f));
    }
    {
        #pragma unroll
        for (int i = 0; i < 2; i++) {
            int s = tid + i * 256, r = s >> 2, c = (s & 3) * 8;
            *(int4*)&Bs[0][r][c] = *(const int4*)&ew2t[(size_t)r * 128 + c];
        }
    }

    // ---- phase 2: hb = h1 @ ew2t^T + eb2, 4 k-steps ----
    fx4 acc2[4] = {};
    for (int it = 0; it < 4; it++) {
        const int cur = it & 1;
        int4 br[2];
        __syncthreads();
        if (it < 3) {
            #pragma unroll
            for (int i = 0; i < 2; i++) {
                int s = tid + i * 256, r = s >> 2, c = (s & 3) * 8;
                br[i] = *(const int4*)&ew2t[(size_t)r * 128 + (it + 1) * 32 + c];
            }
        }
        bh8 af = *(const bh8*)&Hb[wm + l15][it * 32 + l4 * 8];
        #pragma unroll
        for (int nj = 0; nj < 4; nj++) {
            bh8 bf = *(const bh8*)&Bs[cur][wn + nj * 16 + l15][l4 * 8];
            acc2[nj] = __builtin_amdgcn_mfma_f32_16x16x32_bf16(af, bf, acc2[nj], 0, 0, 0);
        }
        if (it < 3) {
            #pragma unroll
            for (int i = 0; i < 2; i++) {
                int s = tid + i * 256, r = s >> 2, c = (s & 3) * 8;
                *(int4*)&Bs[cur ^ 1][r][c] = br[i];
            }
        }
    }
    // hb -> Hb2 (reuse As space); restage Bs[0] = gwt chunk 0 (last cur 1)
    u16 (*Hb2)[136] = (u16(*)[136])&As[0][0];
    #pragma unroll
    for (int nj = 0; nj < 4; nj++) {
        int cl = wn + nj * 16 + l15;
        float bvv = eb2[cl];
        #pragma unroll
        for (int r = 0; r < 4; r++)
            Hb2[wm + l4 * 4 + r][cl] = f2bf(acc2[nj][r] + bvv);
    }
    {
        #pragma unroll
        for (int i = 0; i < 2; i++) {
            int s = tid + i * 256, r = s >> 2, c = (s & 3) * 8;
            *(int4*)&Bs[0][r][c] = *(const int4*)&gwt[(size_t)r * 128 + c];
        }
    }

    // ---- phase 3: hh = hb @ gwt^T, 4 k-steps ----
    fx4 acc3[4] = {};
    for (int it = 0; it < 4; it++) {
        const int cur = it & 1;
        int4 br[2];
        __syncthreads();
        if (it < 3) {
            #pragma unroll
            for (int i = 0; i < 2; i++) {
                int s = tid + i * 256, r = s >> 2, c = (s & 3) * 8;
                br[i] = *(const int4*)&gwt[(size_t)r * 128 + (it + 1) * 32 + c];
            }
        }
        bh8 af = *(const bh8*)&Hb2[wm + l15][it * 32 + l4 * 8];
        #pragma unroll
        for (int nj = 0; nj < 4; nj++) {
            bh8 bf = *(const bh8*)&Bs[cur][wn + nj * 16 + l15][l4 * 8];
            acc3[nj] = __builtin_amdgcn_mfma_f32_16x16x32_bf16(af, bf, acc3[nj], 0, 0, 0);
        }
        if (it < 3) {
            #pragma unroll
            for (int i = 0; i < 2; i++) {
                int s = tid + i * 256, r = s >> 2, c = (s & 3) * 8;
                *(int4*)&Bs[cur ^ 1][r][c] = br[i];
            }
        }
    }

    // hh -> global bf16 + LDS Ct (f32 for the a-dots)
    #pragma unroll
    for (int nj = 0; nj < 4; nj++) {
        int cl = wn + nj * 16 + l15;
        #pragma unroll
        for (int r = 0; r < 4; r++) {
            int rl = wm + l4 * 4 + r;
            float v = acc3[nj][r];
            hhb[(size_t)(m0 + rl) * 128 + cl] = f2bf(v);
            Ct[rl][cl] = v;
        }
    }
    __syncthreads();

    // per-row a_src/a_dst: 8 threads/row, 16 cols each (4 thr per head)
    const int row = tid >> 3, c0 = (tid & 7) * 16, head = c0 >> 6;
    float ps = 0.f, pd = 0.f;
    #pragma unroll
    for (int j = 0; j < 16; j++) {
        float v = Ct[row][c0 + j];
        int cc = (c0 + j) & 63;
        ps += v * gasrc[head * 64 + cc];
        pd += v * gadst[head * 64 + cc];
    }
    ps += __shfl_xor(ps, 1); pd += __shfl_xor(pd, 1);
    ps += __shfl_xor(ps, 2); pd += __shfl_xor(pd, 2);
    if ((tid & 3) == 0) {
        ansrc[(m0 + row) * 2 + head] = ps;
        andst[(m0 + row) * 2 + head] = pd;
    }

    // ---- fused count_edges (counts pre-zeroed in prep) ----
    for (int i = blockIdx.x * 256 + tid; i < E; i += 128 * 256)
        atomicAdd(&counts[edst[i]], 1);
}

// ------------------------------------------------------------------
// fused FFN: part[z] = relu(A @ W1t^T + b1) @ W2t^T   (BF16 partials)
// grid (64, 8): 64 row-blocks x 8 ff-col slices of 256 (4 chunks of 64)
// ------------------------------------------------------------------
__global__ __launch_bounds__(256) void ffn_fused(
    const u16* __restrict__ A, const u16* __restrict__ W1t,
    const float* __restrict__ b1, const u16* __restrict__ W2t,
    u16* __restrict__ part)
{
    __shared__ __align__(16) u16 Ab[64][136];
    __shared__ __align__(16) u16 Wb[64][136];
    __shared__ __align__(16) u16 Sb[64][72];
    const int m0 = blockIdx.x * 64, z = blockIdx.y;
    const int tid = threadIdx.x;
    const int lane = tid & 63, w = tid >> 6;
    const int wm = (w >> 1) * 32;
    const int wn = (w & 1) * 32;
    const int wn2 = (w & 1) * 64;
    const int l15 = lane & 15, l4 = lane >> 4;
    const int sr = tid >> 2, sc = (tid & 3) * 32;

    {   // stage A: 64 rows x 128 k
        const u16* ap = A + (size_t)(m0 + sr) * 128 + sc;
        #pragma unroll
        for (int i = 0; i < 4; i++)
            *(int4*)&Ab[sr][sc + i * 8] = *(const int4*)(ap + i * 8);
    }

    fx4 acc2[2][4] = {};

    for (int chunk = 0; chunk < 4; chunk++) {
        const int ffbase = z * 256 + chunk * 64;
        __syncthreads();
        {   // stage W1 chunk
            const u16* wp = W1t + (size_t)(ffbase + sr) * 128 + sc;
            #pragma unroll
            for (int i = 0; i < 4; i++)
                *(int4*)&Wb[sr][sc + i * 8] = *(const int4*)(wp + i * 8);
        }
        __syncthreads();

        fx4 s[2][2] = {};
        #pragma unroll
        for (int ks = 0; ks < 4; ks++) {
            bh8 af0 = *(const bh8*)&Ab[wm + l15][ks * 32 + l4 * 8];
            bh8 af1 = *(const bh8*)&Ab[wm + 16 + l15][ks * 32 + l4 * 8];
            bh8 bf0 = *(const bh8*)&Wb[wn + l15][ks * 32 + l4 * 8];
            bh8 bf1 = *(const bh8*)&Wb[wn + 16 + l15][ks * 32 + l4 * 8];
            s[0][0] = __builtin_amdgcn_mfma_f32_16x16x32_bf16(af0, bf0, s[0][0], 0, 0, 0);
            s[0][1] = __builtin_amdgcn_mfma_f32_16x16x32_bf16(af0, bf1, s[0][1], 0, 0, 0);
            s[1][0] = __builtin_amdgcn_mfma_f32_16x16x32_bf16(af1, bf0, s[1][0], 0, 0, 0);
            s[1][1] = __builtin_amdgcn_mfma_f32_16x16x32_bf16(af1, bf1, s[1][1], 0, 0, 0);
        }
        #pragma unroll
        for (int mi = 0; mi < 2; mi++)
            #pragma unroll
            for (int nj = 0; nj < 2; nj++) {
                float bv = b1[ffbase + wn + nj * 16 + l15];
                #pragma unroll
                for (int r = 0; r < 4; r++) {
                    float v = fmaxf(s[mi][nj][r] + bv, 0.f);
                    Sb[wm + mi * 16 + l4 * 4 + r][wn + nj * 16 + l15] = f2bf(v);
                }
            }
        __syncthreads();

        #pragma unroll
        for (int ks = 0; ks < 2; ks++) {
            bh8 af0 = *(const bh8*)&Sb[wm + l15][ks * 32 + l4 * 8];
            bh8 af1 = *(const bh8*)&Sb[wm + 16 + l15][ks * 32 + l4 * 8];
            #pragma unroll
            for (int nj = 0; nj < 4; nj++) {
                bh8 bf = *(const bh8*)&W2t[(size_t)(wn2 + nj * 16 + l15) * 2048 + ffbase + ks * 32 + l4 * 8];
                acc2[0][nj] = __builtin_amdgcn_mfma_f32_16x16x32_bf16(af0, bf, acc2[0][nj], 0, 0, 0);
                acc2[1][nj] = __builtin_amdgcn_mfma_f32_16x16x32_bf16(af1, bf, acc2[1][nj], 0, 0, 0);
            }
        }
    }

    u16* cp = part + (size_t)z * 524288;
    #pragma unroll
    for (int mi = 0; mi < 2; mi++)
        #pragma unroll
        for (int nj = 0; nj < 4; nj++) {
            int colg = wn2 + nj * 16 + l15;
            int rowb = m0 + wm + mi * 16 + l4 * 4;
            #pragma unroll
            for (int r = 0; r < 4; r++)
                cp[(size_t)(rowb + r) * 128 + colg] = f2bf(acc2[mi][nj][r]);
        }
}

// shfl-based scan: per-wave inclusive scan + cross-wave LDS combine
__global__ __launch_bounds__(1024) void scan_kernel(const int* __restrict__ counts,
                                                    int* row_start, int* cursor) {
    __shared__ int wsum[16];
    int tid = threadIdx.x, lane = tid & 63, wv = tid >> 6;
    int b = tid * 4;
    int c0 = counts[b], c1 = counts[b+1], c2 = counts[b+2], c3 = counts[b+3];
    int sum = c0 + c1 + c2 + c3;
    int inc = sum;
    #pragma unroll
    for (int off = 1; off < 64; off <<= 1) {
        int v = __shfl_up(inc, off);
        if (lane >= off) inc += v;
    }
    if (lane == 63) wsum[wv] = inc;
    __syncthreads();
    int base = 0;
    #pragma unroll
    for (int i = 0; i < 16; i++) {
        int v = wsum[i];
        base += (i < wv) ? v : 0;
    }
    int excl = base + inc - sum;
    int r0 = excl, r1 = excl + c0, r2 = r1 + c1, r3 = r2 + c2;
    row_start[b] = r0; row_start[b+1] = r1; row_start[b+2] = r2; row_start[b+3] = r3;
    cursor[b] = r0; cursor[b+1] = r1; cursor[b+2] = r2; cursor[b+3] = r3;
    if (tid == 1023) row_start[4096] = base + inc;
}

__global__ void scatter_edges(const int* __restrict__ src, const int* __restrict__ dst,
                              int* cursor, int* csr_src, int E) {
    int i = blockIdx.x * 256 + threadIdx.x;
    if (i < E) { int pos = atomicAdd(&cursor[dst[i]], 1); csr_src[pos] = src[i]; }
}

// ------------------------------------------------------------------
// GAT aggregate: one block (256 thr) per destination node.
// hh gathered as BF16.
// ------------------------------------------------------------------
__global__ __launch_bounds__(256) void gat_aggregate(
    const int* __restrict__ row_start, const int* __restrict__ csr_src,
    const float* __restrict__ an_src, const float* __restrict__ an_dst,
    const u16* __restrict__ hhb, const float* __restrict__ gbias,
    float* __restrict__ y32, u16* __restrict__ yb)
{
    int n = blockIdx.x, tid = threadIdx.x;
    const int lane = tid & 63, wv = tid >> 6;
    int start = row_start[n], end = row_start[n + 1];
    float ad0 = an_dst[n * 2 + 0], ad1 = an_dst[n * 2 + 1];
    __shared__ float rmx[4][2], rsm[4][2];
    __shared__ float sal0[128], sal1[128], sagg[256];
    __shared__ int sidx[128];

    float mx0 = -1e30f, mx1 = -1e30f;
    for (int i = start + tid; i < end; i += 256) {
        int s = csr_src[i];
        float e0 = an_src[s * 2 + 0] + ad0; e0 = e0 > 0.f ? e0 : 0.2f * e0;
        float e1 = an_src[s * 2 + 1] + ad1; e1 = e1 > 0.f ? e1 : 0.2f * e1;
        mx0 = fmaxf(mx0, e0); mx1 = fmaxf(mx1, e1);
    }
    for (int off = 32; off; off >>= 1) { mx0 = fmaxf(mx0, __shfl_down(mx0, off)); mx1 = fmaxf(mx1, __shfl_down(mx1, off)); }
    if (lane == 0) { rmx[wv][0] = mx0; rmx[wv][1] = mx1; }
    __syncthreads();
    mx0 = fmaxf(fmaxf(rmx[0][0], rmx[1][0]), fmaxf(rmx[2][0], rmx[3][0]));
    mx1 = fmaxf(fmaxf(rmx[0][1], rmx[1][1]), fmaxf(rmx[2][1], rmx[3][1]));

    float den0 = 0.f, den1 = 0.f;
    for (int i = start + tid; i < end; i += 256) {
        int s = csr_src[i];
        float e0 = an_src[s * 2 + 0] + ad0; e0 = e0 > 0.f ? e0 : 0.2f * e0;
        float e1 = an_src[s * 2 + 1] + ad1; e1 = e1 > 0.f ? e1 : 0.2f * e1;
        den0 += __expf(e0 - mx0); den1 += __expf(e1 - mx1);
    }
    for (int off = 32; off; off >>= 1) { den0 += __shfl_down(den0, off); den1 += __shfl_down(den1, off); }
    if (lane == 0) { rsm[wv][0] = den0; rsm[wv][1] = den1; }
    __syncthreads();
    den0 = rsm[0][0] + rsm[1][0] + rsm[2][0] + rsm[3][0];
    den1 = rsm[0][1] + rsm[1][1] + rsm[2][1] + rsm[3][1];
    float rd0 = 1.f / den0, rd1 = 1.f / den1;

    const int grp = tid >> 7, ch = tid & 127, head = ch >> 6;
    float agg = 0.f;
    for (int c0 = start; c0 < end; c0 += 128) {
        int cnt = min(128, end - c0);
        __syncthreads();
        if (tid < cnt) {
            int s = csr_src[c0 + tid];
            float e0 = an_src[s * 2 + 0] + ad0; e0 = e0 > 0.f ? e0 : 0.2f * e0;
            float e1 = an_src[s * 2 + 1] + ad1; e1 = e1 > 0.f ? e1 : 0.2f * e1;
            sal0[tid] = __expf(e0 - mx0) * rd0;
            sal1[tid] = __expf(e1 - mx1) * rd1;
            sidx[tid] = s;
        }
        __syncthreads();
        const float* sal = head ? sal1 : sal0;
        for (int j = grp; j < cnt; j += 2)
            agg += sal[j] * bf2f(hhb[(size_t)sidx[j] * 128 + ch]);
    }
    sagg[tid] = agg;
    __syncthreads();
    if (tid < 128) {
        float v = sagg[tid] + sagg[tid + 128] + gbias[tid];
        y32[(size_t)n * 128 + tid] = v;
        yb[(size_t)n * 128 + tid] = f2bf(v);
    }
}

// ------------------------------------------------------------------
// flash attention partial: QBLK=128 q-rows/block, grid (32, NH, 8
// chunks of 512 keys). O partials written BF16 (cvt_pk).
// ------------------------------------------------------------------
__global__ __launch_bounds__(256) void flash_attn_part(
    const u16* __restrict__ q, const u16* __restrict__ k,
    const u16* __restrict__ vt, u16* __restrict__ po,
    float* __restrict__ pm, float* __restrict__ pl)
{
    __shared__ __align__(16) u16 Kb[2][64][40];
    __shared__ __align__(16) u16 Vb[2][32][72];
    __shared__ __align__(16) u16 Ps[4][32][72];
    const int q0 = blockIdx.x * 128, h = blockIdx.y, ch = blockIdx.z;
    const int tid = threadIdx.x;
    const int w = tid >> 6, lane = tid & 63, l15 = lane & 15, l4 = lane >> 4;

    bh8 qf0 = *(const bh8*)&q[(size_t)(q0 + w * 32 + l15) * 256 + h * 32 + l4 * 8];
    bh8 qf1 = *(const bh8*)&q[(size_t)(q0 + w * 32 + 16 + l15) * 256 + h * 32 + l4 * 8];

    const int skey = tid >> 2, sds = (tid & 3) * 8;   // K staging: 64 keys x 32 d
    const int svd = tid >> 3, svk = (tid & 7) * 8;    // V staging: 32 d x 64 keys
    const u16* kgp = &k[(size_t)(ch * 512 + skey) * 256 + h * 32 + sds];
    const u16* vgp = &vt[(size_t)(h * 32 + svd) * 4096 + ch * 512 + svk];

    fx4 o00 = {0,0,0,0}, o01 = {0,0,0,0}, o10 = {0,0,0,0}, o11 = {0,0,0,0};
    float M0 = -1e30f, L0 = 0.f, M1 = -1e30f, L1 = 0.f;

    *(int4*)&Kb[0][skey][sds] = *(const int4*)kgp;
    *(int4*)&Vb[0][svd][svk] = *(const int4*)vgp;

    for (int ti = 0; ti < 8; ti++) {
        const int cur = ti & 1;
        int4 kr, vr;
        __syncthreads();
        if (ti < 7) {   // issue next-tile loads AFTER barrier; compute hides latency
            kr = *(const int4*)(kgp + (size_t)(ti + 1) * 64 * 256);
            vr = *(const int4*)(vgp + (ti + 1) * 64);
        }

        fx4 s0[4], s1[4];
        #pragma unroll
        for (int sub = 0; sub < 4; sub++) {
            bh8 kf = *(const bh8*)&Kb[cur][sub * 16 + l15][l4 * 8];
            fx4 z = {0,0,0,0};
            s0[sub] = __builtin_amdgcn_mfma_f32_16x16x32_bf16(kf, qf0, z, 0, 0, 0);
            s1[sub] = __builtin_amdgcn_mfma_f32_16x16x32_bf16(kf, qf1, z, 0, 0, 0);
        }
        // ---- softmax half 0 ----
        {
            float t0 = fmaxf(fmaxf(s0[0][0], s0[0][1]), s0[0][2]);
            float t1 = fmaxf(fmaxf(s0[0][3], s0[1][0]), s0[1][1]);
            float t2 = fmaxf(fmaxf(s0[1][2], s0[1][3]), s0[2][0]);
            float t3 = fmaxf(fmaxf(s0[2][1], s0[2][2]), s0[2][3]);
            float t4 = fmaxf(fmaxf(s0[3][0], s0[3][1]), s0[3][2]);
            float pmax = fmaxf(fmaxf(fmaxf(t0, t1), t2), fmaxf(fmaxf(t3, t4), s0[3][3]));
            pmax = fmaxf(pmax, __shfl_xor(pmax, 16));
            pmax = fmaxf(pmax, __shfl_xor(pmax, 32));
            if (!__all(pmax - M0 <= 8.0f)) {
                float f = __builtin_amdgcn_exp2f(M0 - pmax);
                M0 = pmax;
                o00 *= f; o01 *= f; L0 *= f;
            }
            #pragma unroll
            for (int sub = 0; sub < 4; sub++)
                #pragma unroll
                for (int r = 0; r < 4; r++)
                    s0[sub][r] = __builtin_amdgcn_exp2f(s0[sub][r] - M0);
            float ss0 = (s0[0][0] + s0[0][1]) + (s0[0][2] + s0[0][3]);
            float ss1 = (s0[1][0] + s0[1][1]) + (s0[1][2] + s0[1][3]);
            float ss2 = (s0[2][0] + s0[2][1]) + (s0[2][2] + s0[2][3]);
            float ss3 = (s0[3][0] + s0[3][1]) + (s0[3][2] + s0[3][3]);
            float lsum = (ss0 + ss1) + (ss2 + ss3);
            lsum += __shfl_xor(lsum, 16);
            lsum += __shfl_xor(lsum, 32);
            L0 += lsum;
        }
        // ---- softmax half 1 ----
        {
            float t0 = fmaxf(fmaxf(s1[0][0], s1[0][1]), s1[0][2]);
            float t1 = fmaxf(fmaxf(s1[0][3], s1[1][0]), s1[1][1]);
            float t2 = fmaxf(fmaxf(s1[1][2], s1[1][3]), s1[2][0]);
            float t3 = fmaxf(fmaxf(s1[2][1], s1[2][2]), s1[2][3]);
            float t4 = fmaxf(fmaxf(s1[3][0], s1[3][1]), s1[3][2]);
            float pmax = fmaxf(fmaxf(fmaxf(t0, t1), t2), fmaxf(fmaxf(t3, t4), s1[3][3]));
            pmax = fmaxf(pmax, __shfl_xor(pmax, 16));
            pmax = fmaxf(pmax, __shfl_xor(pmax, 32));
            if (!__all(pmax - M1 <= 8.0f)) {
                float f = __builtin_amdgcn_exp2f(M1 - pmax);
                M1 = pmax;
                o10 *= f; o11 *= f; L1 *= f;
            }
            #pragma unroll
            for (int sub = 0; sub < 4; sub++)
                #pragma unroll
                for (int r = 0; r < 4; r++)
                    s1[sub][r] = __builtin_amdgcn_exp2f(s1[sub][r] - M1);
            float ss0 = (s1[0][0] + s1[0][1]) + (s1[0][2] + s1[0][3]);
            float ss1 = (s1[1][0] + s1[1][1]) + (s1[1][2] + s1[1][3]);
            float ss2 = (s1[2][0] + s1[2][1]) + (s1[2][2] + s1[2][3]);
            float ss3 = (s1[3][0] + s1[3][1]) + (s1[3][2] + s1[3][3]);
            float lsum = (ss0 + ss1) + (ss2 + ss3);
            lsum += __shfl_xor(lsum, 16);
            lsum += __shfl_xor(lsum, 32);
            L1 += lsum;
        }

        // pack P^T into Ps[w][q][key] (wave-private)
        #pragma unroll
        for (int sub = 0; sub < 4; sub++) {
            u32x2 pk0 = { cvtpk(s0[sub][0], s0[sub][1]), cvtpk(s0[sub][2], s0[sub][3]) };
            *(u32x2*)&Ps[w][l15][sub * 16 + l4 * 4] = pk0;
            u32x2 pk1 = { cvtpk(s1[sub][0], s1[sub][1]), cvtpk(s1[sub][2], s1[sub][3]) };
            *(u32x2*)&Ps[w][16 + l15][sub * 16 + l4 * 4] = pk1;
        }

        // PV: O^T += V^T @ P^T (both halves)
        #pragma unroll
        for (int kc = 0; kc < 2; kc++) {
            bh8 bfA = *(const bh8*)&Ps[w][l15][kc * 32 + l4 * 8];
            bh8 bfB = *(const bh8*)&Ps[w][16 + l15][kc * 32 + l4 * 8];
            bh8 af0 = *(const bh8*)&Vb[cur][l15][kc * 32 + l4 * 8];
            bh8 af1 = *(const bh8*)&Vb[cur][16 + l15][kc * 32 + l4 * 8];
            o00 = __builtin_amdgcn_mfma_f32_16x16x32_bf16(af0, bfA, o00, 0, 0, 0);
            o01 = __builtin_amdgcn_mfma_f32_16x16x32_bf16(af1, bfA, o01, 0, 0, 0);
            o10 = __builtin_amdgcn_mfma_f32_16x16x32_bf16(af0, bfB, o10, 0, 0, 0);
            o11 = __builtin_amdgcn_mfma_f32_16x16x32_bf16(af1, bfB, o11, 0, 0, 0);
        }

        if (ti < 7) {   // write next tile (vmcnt waits land here, after compute)
            *(int4*)&Kb[cur ^ 1][skey][sds] = kr;
            *(int4*)&Vb[cur ^ 1][svd][svk] = vr;
        }
    }
    const int base = (blockIdx.x * 4 + h) * 8 + ch;
    const int qA = w * 32 + l15, qB = qA + 16;
    {
        u32x2 wA0 = { cvtpk(o00[0], o00[1]), cvtpk(o00[2], o00[3]) };
        u32x2 wA1 = { cvtpk(o01[0], o01[1]), cvtpk(o01[2], o01[3]) };
        *(u32x2*)&po[(size_t)(base * 128 + qA) * 32 + l4 * 4]      = wA0;
        *(u32x2*)&po[(size_t)(base * 128 + qA) * 32 + 16 + l4 * 4] = wA1;
        u32x2 wB0 = { cvtpk(o10[0], o10[1]), cvtpk(o10[2], o10[3]) };
        u32x2 wB1 = { cvtpk(o11[0], o11[1]), cvtpk(o11[2], o11[3]) };
        *(u32x2*)&po[(size_t)(base * 128 + qB) * 32 + l4 * 4]      = wB0;
        *(u32x2*)&po[(size_t)(base * 128 + qB) * 32 + 16 + l4 * 4] = wB1;
    }
    if (l4 == 0) {
        pm[base * 128 + qA] = M0; pl[base * 128 + qA] = L0;
        pm[base * 128 + qB] = M1; pl[base * 128 + qB] = L1;
    }
}

// ------------------------------------------------------------------
// fused combine(8 KV-chunks, bf16 partials) + O-proj + residual + LN.
// ------------------------------------------------------------------
__global__ __launch_bounds__(256) void oproj_cln(
    const u16* __restrict__ po, const float* __restrict__ pm,
    const float* __restrict__ pl, const u16* __restrict__ Bt,
    const float* __restrict__ bias, const float* __restrict__ g,
    const float* __restrict__ b,
    float* __restrict__ y32, u16* __restrict__ yb)
{
    __shared__ __align__(16) u16 Ab[32][136];
    __shared__ __align__(16) u16 Bs[2][128][40];
    __shared__ float Ct[32][132];
    const int m0 = blockIdx.x * 32;
    const int tid = threadIdx.x;
    const int lane = tid & 63, w = tid >> 6;
    const int wm = (w >> 1) * 16, wn = (w & 1) * 64;
    const int l15 = lane & 15, l4 = lane >> 4;

    {   // combine 8 KV-chunk partials into A tile (bf16)
        const int row = tid >> 3, c0 = (tid & 7) * 16;
        const int gr = m0 + row, qb = gr >> 7, r1 = gr & 127, h = c0 >> 5;
        const int rb = (qb * 4 + h) * 8;
        float ms = -1e30f;
        float mv[8];
        #pragma unroll
        for (int c = 0; c < 8; c++) { mv[c] = pm[(rb + c) * 128 + r1]; ms = fmaxf(ms, mv[c]); }
        float wc[8], lsum = 0.f;
        #pragma unroll
        for (int c = 0; c < 8; c++) {
            wc[c] = __builtin_amdgcn_exp2f(mv[c] - ms);
            lsum += wc[c] * pl[(rb + c) * 128 + r1];
        }
        float rl = 1.f / lsum;
        const int cb = c0 & 31;
        float o[16] = {};
        #pragma unroll
        for (int c = 0; c < 8; c++) {
            const u16* pp = po + ((size_t)((rb + c) * 128 + r1)) * 32 + cb;
            s4 v0 = *(const s4*)pp;
            s4 v1 = *(const s4*)(pp + 4);
            s4 v2 = *(const s4*)(pp + 8);
            s4 v3 = *(const s4*)(pp + 12);
            #pragma unroll
            for (int j = 0; j < 4; j++) {
                o[j]      += wc[c] * bf2f((u16)v0[j]);
                o[4 + j]  += wc[c] * bf2f((u16)v1[j]);
                o[8 + j]  += wc[c] * bf2f((u16)v2[j]);
                o[12 + j] += wc[c] * bf2f((u16)v3[j]);
            }
        }
        #pragma unroll
        for (int j = 0; j < 16; j++)
            Ab[row][c0 + j] = f2bf(o[j] * rl);
    }

    {   // stage Bs[0]
        const int brow = tid >> 2, bkq = (tid & 3) * 8;
        *(int4*)&Bs[0][brow][bkq]      = *(const int4*)&Bt[(size_t)brow * 128 + bkq];
        *(int4*)&Bs[0][brow + 64][bkq] = *(const int4*)&Bt[(size_t)(brow + 64) * 128 + bkq];
    }

    fx4 acc[4] = {};
    const int brow = tid >> 2, bkq = (tid & 3) * 8;
    for (int it = 0; it < 4; it++) {
        const int cur = it & 1;
        int4 br0, br1;
        __syncthreads();
        if (it < 3) {
            br0 = *(const int4*)&Bt[(size_t)brow * 128 + (it + 1) * 32 + bkq];
            br1 = *(const int4*)&Bt[(size_t)(brow + 64) * 128 + (it + 1) * 32 + bkq];
        }
        bh8 af = *(const bh8*)&Ab[wm + l15][it * 32 + l4 * 8];
        #pragma unroll
        for (int nj = 0; nj < 4; nj++) {
            bh8 bf = *(const bh8*)&Bs[cur][wn + nj * 16 + l15][l4 * 8];
            acc[nj] = __builtin_amdgcn_mfma_f32_16x16x32_bf16(af, bf, acc[nj], 0, 0, 0);
        }
        if (it < 3) {
            *(int4*)&Bs[cur ^ 1][brow][bkq]      = br0;
            *(int4*)&Bs[cur ^ 1][brow + 64][bkq] = br1;
        }
    }

    #pragma unroll
    for (int nj = 0; nj < 4; nj++) {
        int cl = wn + nj * 16 + l15;
        float bvv = bias[cl];
        #pragma unroll
        for (int r = 0; r < 4; r++) {
            int rl = wm + l4 * 4 + r;
            Ct[rl][cl] = acc[nj][r] + bvv + y32[(size_t)(m0 + rl) * 128 + cl];
        }
    }
    __syncthreads();

    const int row = tid >> 3, c0 = (tid & 7) * 16;
    float s1 = 0.f, s2 = 0.f;
    #pragma unroll
    for (int j = 0; j < 16; j++) { float v = Ct[row][c0 + j]; s1 += v; s2 += v * v; }
    #pragma unroll
    for (int off = 1; off < 8; off <<= 1) { s1 += __shfl_xor(s1, off); s2 += __shfl_xor(s2, off); }
    float mean = s1 * (1.f / 128.f);
    float var = s2 * (1.f / 128.f) - mean * mean;
    float rstd = rsqrtf(var + 1e-5f);
    #pragma unroll
    for (int j = 0; j < 16; j++) {
        int col = c0 + j;
        float o = (Ct[row][col] - mean) * rstd * g[col] + b[col];
        y32[(size_t)(m0 + row) * 128 + col] = o;
        yb[(size_t)(m0 + row) * 128 + col] = f2bf(o);
    }
}

// ------------------------------------------------------------------
// residual add + nz split-K bf16 partials + bias + LayerNorm
// ------------------------------------------------------------------
__global__ __launch_bounds__(128) void add_ln_p(
    const float* __restrict__ y, const u16* __restrict__ part, int nz,
    const float* __restrict__ bias,
    const float* __restrict__ g, const float* __restrict__ b,
    float* __restrict__ out32, u16* __restrict__ outb)
{
    int n = blockIdx.x, tid = threadIdx.x;
    float v = y[(size_t)n * 128 + tid] + bias[tid];
    for (int z = 0; z < nz; z++) v += bf2f(part[(size_t)z * 524288 + n * 128 + tid]);
    float sacc = v;
    for (int off = 32; off; off >>= 1) sacc += __shfl_down(sacc, off);
    __shared__ float sm[2], sv[2];
    if ((tid & 63) == 0) sm[tid >> 6] = sacc;
    __syncthreads();
    float mean = (sm[0] + sm[1]) * (1.f / 128.f);
    float d = v - mean;
    float qacc = d * d;
    for (int off = 32; off; off >>= 1) qacc += __shfl_down(qacc, off);
    if ((tid & 63) == 0) sv[tid >> 6] = qacc;
    __syncthreads();
    float var = (sv[0] + sv[1]) * (1.f / 128.f);
    float o = d * rsqrtf(var + 1e-5f) * g[tid] + b[tid];
    out32[(size_t)n * 128 + tid] = o;
    outb[(size_t)n * 128 + tid] = f2bf(o);
}

// ------------------------------------------------------------------
extern "C" void kernel_launch(void* const* d_in, const int* in_sizes, int n_in,
                              void* d_out, int out_size, void* d_ws, size_t ws_size,
                              hipStream_t stream)
{
    const float* x     = (const float*)d_in[0];
    const int*   ei    = (const int*)  d_in[1];
    const float* ew1   = (const float*)d_in[2];
    const float* eb1   = (const float*)d_in[3];
    const float* ew2   = (const float*)d_in[4];
    const float* eb2   = (const float*)d_in[5];
    const float* gw    = (const float*)d_in[6];
    const float* gasrc = (const float*)d_in[7];
    const float* gadst = (const float*)d_in[8];
    const float* gbias = (const float*)d_in[9];
    const float* wq    = (const float*)d_in[10];
    const float* bq    = (const float*)d_in[11];
    const float* wk    = (const float*)d_in[12];
    const float* bk    = (const float*)d_in[13];
    const float* wv    = (const float*)d_in[14];
    const float* bv    = (const float*)d_in[15];
    const float* wo    = (const float*)d_in[16];
    const float* bo    = (const float*)d_in[17];
    const float* ln1g  = (const float*)d_in[18];
    const float* ln1b  = (const float*)d_in[19];
    const float* ln2g  = (const float*)d_in[20];
    const float* ln2b  = (const float*)d_in[21];
    const float* w1    = (const float*)d_in[22];
    const float* b1    = (const float*)d_in[23];
    const float* w2    = (const float*)d_in[24];
    const float* b2    = (const float*)d_in[25];

    const int E = in_sizes[1] / 2;
    const int* esrc = ei;
    const int* edst = ei + E;

    char* p = (char*)d_ws;
    auto alloc = [&](size_t bytes) -> void* {
        void* r = (void*)p;
        p += (bytes + 255) & ~(size_t)255;
        return r;
    };
    u16* xb    = (u16*)alloc(4096 * 256 * 2);
    u16* ew1t  = (u16*)alloc(128 * 256 * 2);
    u16* ew2t  = (u16*)alloc(128 * 128 * 2);
    u16* gwt   = (u16*)alloc(128 * 128 * 2);
    u16* wqkvt = (u16*)alloc(2 * 384 * 128 * 2);
    float* bqkv = (float*)alloc(2 * 384 * 4);
    u16* wot   = (u16*)alloc(2 * 128 * 128 * 2);
    u16* w1t   = (u16*)alloc(2 * 2048 * 128 * 2);
    u16* w2t   = (u16*)alloc(2 * 128 * 2048 * 2);
    u16* hhb   = (u16*)alloc(4096 * 128 * 2);
    float* ansrc = (float*)alloc(4096 * 2 * 4);
    float* andst = (float*)alloc(4096 * 2 * 4);
    int* counts    = (int*)alloc(4096 * 4);
    int* row_start = (int*)alloc(4097 * 4);
    int* cursor    = (int*)alloc(4096 * 4);
    int* csr_src   = (int*)alloc((size_t)E * 4);
    float* y32 = (float*)alloc(4096 * 128 * 4);
    u16* yb    = (u16*)alloc(4096 * 128 * 2);
    u16* qkvb  = (u16*)alloc((size_t)4096 * 256 * 2);   // Q,K only (pitch 256)
    u16* vtb   = (u16*)alloc(4096 * 128 * 2);           // V transposed [128][4096]
    u16* po    = (u16*)alloc((size_t)32 * 4 * 8 * 128 * 32 * 2);
    float* pm  = (float*)alloc(32 * 4 * 8 * 128 * 4);
    float* pl  = (float*)alloc(32 * 4 * 8 * 128 * 4);
    u16* ffpart = (u16*)alloc((size_t)8 * 4096 * 128 * 2);

    // ---- prep (includes counts zeroing) ----
    prep_kernel<<<449, 256, 0, stream>>>(x, ew1, ew2, gw, wq, wk, wv, wo, w1, w2,
                                         bq, bk, bv,
                                         xb, ew1t, ew2t, gwt, wqkvt, bqkv, wot, w1t, w2t,
                                         counts);

    // ---- fused encoder + GAT front-end + edge counting ----
    encoder_gat<<<128, 256, 0, stream>>>(xb, ew1t, eb1, ew2t, eb2, gwt,
                                         gasrc, gadst, hhb, ansrc, andst, counts, edst, E);
    scan_kernel<<<1, 1024, 0, stream>>>(counts, row_start, cursor);
    scatter_edges<<<(E + 255) / 256, 256, 0, stream>>>(esrc, edst, cursor, csr_src, E);
    gat_aggregate<<<4096, 256, 0, stream>>>(row_start, csr_src, ansrc, andst, hhb, gbias, y32, yb);

    // ---- transformer layers ----
    for (int l = 0; l < 2; l++) {
        gemm_bf16<<<dim3(64, 6), 256, 0, stream>>>(yb, wqkvt + l * 49152, bqkv + l * 384, nullptr, qkvb, nullptr, vtb, 4096, 384, 128, 0, 128, 256);
        flash_attn_part<<<dim3(32, 4, 8), 256, 0, stream>>>(qkvb, qkvb + 128, vtb, po, pm, pl);
        oproj_cln<<<128, 256, 0, stream>>>(po, pm, pl, wot + l * 16384, bo + l * 128, ln1g + l * 128, ln1b + l * 128, y32, yb);
        ffn_fused<<<dim3(64, 8), 256, 0, stream>>>(yb, w1t + (size_t)l * 262144, b1 + l * 2048, w2t + (size_t)l * 262144, ffpart);
        float* outp = (l == 1) ? (float*)d_out : y32;
        add_ln_p<<<4096, 128, 0, stream>>>(y32, ffpart, 8, b2 + l * 128, ln2g + l * 128, ln2b + l * 128, outp, yb);
    }
}